// Round 3
// baseline (141.960 us; speedup 1.0000x reference)
//
#include <hip/hip_runtime.h>
#include <hip/hip_bf16.h>
#include <stdint.h>

#define EMBED 1024
#define HEADS 16
#define HDIM 64
#define BATCH 2
#define SEQ 2048
#define NROWS (BATCH*SEQ)

typedef __attribute__((ext_vector_type(8))) short short8;
typedef __attribute__((ext_vector_type(4))) float f32x4;

#define LOG2E 1.44269504088896f

__device__ __forceinline__ unsigned short f2bf(float f) {
    __hip_bfloat16 b = __float2bfloat16(f);
    return *reinterpret_cast<unsigned short*>(&b);
}

__device__ __forceinline__ void g2l16(const void* g, void* l) {
    __builtin_amdgcn_global_load_lds(
        (const __attribute__((address_space(1))) unsigned int*)g,
        (__attribute__((address_space(3))) unsigned int*)l, 16, 0, 0);
}

// ---------------- cast x (fp32 -> bf16), vectorized ----------------
__global__ void cast_x_kernel(const float* __restrict__ x,
                              unsigned short* __restrict__ xb, int n4) {
    int i = blockIdx.x * blockDim.x + threadIdx.x;
    if (i < n4) {
        float4 v = reinterpret_cast<const float4*>(x)[i];
        ushort4 o;
        o.x = f2bf(v.x); o.y = f2bf(v.y); o.z = f2bf(v.z); o.w = f2bf(v.w);
        reinterpret_cast<ushort4*>(xb)[i] = o;
    }
}

// ---------------- transpose + cast W [in][out] fp32 -> Wt [out][in] bf16 ----
__global__ void transW_kernel(const float* __restrict__ W,
                              unsigned short* __restrict__ Wt) {
    __shared__ float tile[32][33];
    int tx = threadIdx.x, ty = threadIdx.y;
#pragma unroll
    for (int r = 0; r < 4; r++) {
        int i = blockIdx.y * 32 + ty + r * 8;
        int o = blockIdx.x * 32 + tx;
        tile[ty + r * 8][tx] = W[(size_t)i * EMBED + o];
    }
    __syncthreads();
    int i2 = blockIdx.y * 32 + tx;
#pragma unroll
    for (int r = 0; r < 4; r++) {
        int o2 = blockIdx.x * 32 + ty + r * 8;
        Wt[(size_t)o2 * EMBED + i2] = f2bf(tile[tx][ty + r * 8]);
    }
}

// ---------------- GEMM: C[M][N] = A[M][K] * B[N][K]^T  (bf16 in, fp32 acc) --
template<int MODE>
__global__ __launch_bounds__(256)
void gemm_kernel(const unsigned short* __restrict__ A,
                 const unsigned short* __restrict__ B,
                 int K,
                 unsigned short* __restrict__ Qo,
                 unsigned short* __restrict__ Ko,
                 unsigned short* __restrict__ Vto,
                 const float* __restrict__ bq,
                 const float* __restrict__ bk,
                 const float* __restrict__ bvv,
                 float* __restrict__ Co,
                 const float* __restrict__ bo) {
    __shared__ __attribute__((aligned(16))) unsigned short As[128 * 64];
    __shared__ __attribute__((aligned(16))) unsigned short Bs[128 * 64];
    const int t = threadIdx.x;
    const int lane = t & 63;
    const int w = t >> 6;
    const int wr = w >> 1, wc = w & 1;
    const int l15 = lane & 15, l16 = lane >> 4;
    const int m0 = blockIdx.y * 128;
    const int n0 = blockIdx.x * 128;

    f32x4 acc[4][4];
#pragma unroll
    for (int i = 0; i < 4; i++)
#pragma unroll
        for (int j = 0; j < 4; j++) acc[i][j] = (f32x4){0.f, 0.f, 0.f, 0.f};

    for (int k0 = 0; k0 < K; k0 += 64) {
        __syncthreads();
#pragma unroll
        for (int i = 0; i < 4; i++) {
            int c = i * 256 + t;
            int row = c >> 3;
            int lc = (c & 7) ^ (row & 7);
            g2l16(A + (size_t)(m0 + row) * K + k0 + lc * 8,
                  As + (size_t)(i * 256 + (t & ~63)) * 8);
        }
#pragma unroll
        for (int i = 0; i < 4; i++) {
            int c = i * 256 + t;
            int row = c >> 3;
            int lc = (c & 7) ^ (row & 7);
            g2l16(B + (size_t)(n0 + row) * K + k0 + lc * 8,
                  Bs + (size_t)(i * 256 + (t & ~63)) * 8);
        }
        __syncthreads();
#pragma unroll
        for (int kk = 0; kk < 2; kk++) {
            short8 a[4], b[4];
#pragma unroll
            for (int ai = 0; ai < 4; ai++) {
                int row = wr * 64 + ai * 16 + l15;
                int ch = kk * 4 + l16;
                a[ai] = *reinterpret_cast<const short8*>(
                    As + row * 64 + ((ch ^ (row & 7)) << 3));
            }
#pragma unroll
            for (int bj = 0; bj < 4; bj++) {
                int row = wc * 64 + bj * 16 + l15;
                int ch = kk * 4 + l16;
                b[bj] = *reinterpret_cast<const short8*>(
                    Bs + row * 64 + ((ch ^ (row & 7)) << 3));
            }
            __builtin_amdgcn_s_setprio(1);
#pragma unroll
            for (int ai = 0; ai < 4; ai++)
#pragma unroll
                for (int bj = 0; bj < 4; bj++)
                    acc[ai][bj] = __builtin_amdgcn_mfma_f32_16x16x32_bf16(
                        a[ai], b[bj], acc[ai][bj], 0, 0, 0);
            __builtin_amdgcn_s_setprio(0);
        }
    }

    if (MODE == 0) {
        const int which = n0 >> 10;        // 0=Q 1=K 2=V
        const int coln = n0 & 1023;
        const float* bias = which == 0 ? bq : (which == 1 ? bk : bvv);
        // Q pre-scaled by softmax scale * LOG2E (softmax done in log2 domain)
        const float scale = which == 0 ? 0.125f * LOG2E : 1.0f;
#pragma unroll
        for (int ai = 0; ai < 4; ai++) {
            int rowb = m0 + wr * 64 + ai * 16 + l16 * 4;
            int b_ = rowb >> 11;
            int s = rowb & 2047;
#pragma unroll
            for (int bj = 0; bj < 4; bj++) {
                int col = coln + wc * 64 + bj * 16 + l15;
                float bsv = bias[col];
                int h = col >> 6, d = col & 63;
                if (which < 2) {
                    unsigned short* dst = (which == 0) ? Qo : Ko;
                    size_t base = ((size_t)(b_ * HEADS + h)) * SEQ * HDIM;
#pragma unroll
                    for (int r = 0; r < 4; r++) {
                        float v = (acc[ai][bj][r] + bsv) * scale;
                        dst[base + (size_t)(s + r) * HDIM + d] = f2bf(v);
                    }
                } else {
                    ushort4 pk;
                    pk.x = f2bf(acc[ai][bj][0] + bsv);
                    pk.y = f2bf(acc[ai][bj][1] + bsv);
                    pk.z = f2bf(acc[ai][bj][2] + bsv);
                    pk.w = f2bf(acc[ai][bj][3] + bsv);
                    size_t off = ((size_t)(b_ * HEADS + h) * HDIM + d) * SEQ + s;
                    *reinterpret_cast<ushort4*>(Vto + off) = pk;
                }
            }
        }
    } else {
#pragma unroll
        for (int ai = 0; ai < 4; ai++) {
            int rowb = m0 + wr * 64 + ai * 16 + l16 * 4;
#pragma unroll
            for (int bj = 0; bj < 4; bj++) {
                int col = n0 + wc * 64 + bj * 16 + l15;
                float bsv = bo[col];
#pragma unroll
                for (int r = 0; r < 4; r++)
                    Co[(size_t)(rowb + r) * EMBED + col] = acc[ai][bj][r] + bsv;
            }
        }
    }
}

// ---------------- causal flash attention (persistent work-stealing) ---------
// Q,K: [bh][s][64] bf16 (Q pre-scaled by 0.125*LOG2E); V: [bh][64][s] bf16.
// O: [b*s][1024] bf16. Unit = (qtile of 128 rows, bh), 512 units ordered
// heavy-first; 768 persistent blocks steal units via global atomic counter.
#define N_UNITS 512

__device__ __forceinline__ void stage_kv(const unsigned short* __restrict__ Kg,
                                         const unsigned short* __restrict__ Vg,
                                         int kv0, unsigned short* Ksb,
                                         unsigned short* Vsb, int t) {
#pragma unroll
    for (int i = 0; i < 2; i++) {          // K tile [64 keys][64 d]
        int c = i * 256 + t;
        int row = c >> 3;
        int lc = (c & 7) ^ (row & 7);
        g2l16(Kg + (size_t)(kv0 + row) * HDIM + lc * 8,
              Ksb + (i * 256 + (t & ~63)) * 8);
    }
#pragma unroll
    for (int i = 0; i < 2; i++) {          // V^T tile [64 d][64 keys]
        int c = i * 256 + t;
        int d = c >> 3;
        int lc = (c & 7) ^ (d & 7);
        g2l16(Vg + (size_t)d * SEQ + kv0 + lc * 8,
              Vsb + (i * 256 + (t & ~63)) * 8);
    }
}

__global__ __launch_bounds__(256, 3)
void attn_kernel(const unsigned short* __restrict__ Q,
                 const unsigned short* __restrict__ Kk,
                 const unsigned short* __restrict__ Vt,
                 unsigned short* __restrict__ O,
                 int* __restrict__ unit_counter) {
    __shared__ __attribute__((aligned(16))) unsigned short Ks[2][64 * 64];
    __shared__ __attribute__((aligned(16))) unsigned short Vs[2][64 * 64];
    __shared__ __attribute__((aligned(16))) unsigned short Ps[4][32 * 64];
    __shared__ int s_unit;

    const int t = threadIdx.x;
    const int lane = t & 63;
    const int w = t >> 6;
    const int l15 = lane & 15, l16 = lane >> 4;

    for (;;) {
        if (t == 0) s_unit = atomicAdd(unit_counter, 1);
        __syncthreads();
        const int u = s_unit;
        if (u >= N_UNITS) return;
        // heavy-first: qtile 15 down to 0, bh inner
        const int qi = 15 - (u >> 5);
        const int bh = u & 31;
        const int q0 = qi * 128;
        const size_t base = (size_t)bh * SEQ * HDIM;
        const unsigned short* Kg = Kk + base;
        const unsigned short* Vg = Vt + base;
        const int qrow0 = q0 + w * 32;

        // Q fragments (B-operand) straight from global
        short8 qf[2][2];
        {
            const unsigned short* Qg = Q + base + (size_t)qrow0 * HDIM;
#pragma unroll
            for (int qb = 0; qb < 2; qb++)
#pragma unroll
                for (int kc = 0; kc < 2; kc++)
                    qf[qb][kc] = *reinterpret_cast<const short8*>(
                        Qg + (qb * 16 + l15) * HDIM + (kc * 4 + l16) * 8);
        }

        f32x4 oacc[2][4];
#pragma unroll
        for (int qb = 0; qb < 2; qb++)
#pragma unroll
            for (int nd = 0; nd < 4; nd++)
                oacc[qb][nd] = (f32x4){0.f, 0.f, 0.f, 0.f};
        float m_run[2] = {-1e30f, -1e30f};
        float l_run[2] = {0.f, 0.f};

        const int ntiles = (q0 >> 6) + 2;

        stage_kv(Kg, Vg, 0, Ks[0], Vs[0], t);
        __syncthreads();

        for (int tk = 0; tk < ntiles; tk++) {
            const int kv0 = tk * 64;
            const int cur = tk & 1;
            if (tk + 1 < ntiles)
                stage_kv(Kg, Vg, kv0 + 64, Ks[cur ^ 1], Vs[cur ^ 1], t);

            if (kv0 <= qrow0 + 31) {
                const unsigned short* Kb = Ks[cur];
                const unsigned short* Vb = Vs[cur];
                // ---- S^T = K * Q^T : rows = keys, cols = q
                f32x4 sc[2][4];
#pragma unroll
                for (int qb = 0; qb < 2; qb++)
#pragma unroll
                    for (int kb = 0; kb < 4; kb++)
                        sc[qb][kb] = (f32x4){0.f, 0.f, 0.f, 0.f};
#pragma unroll
                for (int kc = 0; kc < 2; kc++) {
                    short8 ka[4];
#pragma unroll
                    for (int kb = 0; kb < 4; kb++) {
                        int row = kb * 16 + l15;
                        ka[kb] = *reinterpret_cast<const short8*>(
                            Kb + row * 64 + (((kc * 4 + l16) ^ (row & 7)) << 3));
                    }
                    __builtin_amdgcn_s_setprio(1);
#pragma unroll
                    for (int qb = 0; qb < 2; qb++)
#pragma unroll
                        for (int kb = 0; kb < 4; kb++)
                            sc[qb][kb] = __builtin_amdgcn_mfma_f32_16x16x32_bf16(
                                ka[kb], qf[qb][kc], sc[qb][kb], 0, 0, 0);
                    __builtin_amdgcn_s_setprio(0);
                }
                // ---- causal mask (diagonal tiles only)
                if (kv0 + 63 > qrow0) {
#pragma unroll
                    for (int qb = 0; qb < 2; qb++) {
                        int q = qrow0 + qb * 16 + l15;
#pragma unroll
                        for (int kb = 0; kb < 4; kb++)
#pragma unroll
                            for (int r = 0; r < 4; r++) {
                                int k = kv0 + kb * 16 + l16 * 4 + r;
                                sc[qb][kb][r] = (k > q) ? -1e30f : sc[qb][kb][r];
                            }
                    }
                }
                // ---- row max (in-register + 2 shuffles), defer-rescale vote
                float vmax[2];
                bool need = false;
#pragma unroll
                for (int qb = 0; qb < 2; qb++) {
                    float mx = -1e30f;
#pragma unroll
                    for (int kb = 0; kb < 4; kb++) {
                        float a = fmaxf(fmaxf(sc[qb][kb][0], sc[qb][kb][1]),
                                        fmaxf(sc[qb][kb][2], sc[qb][kb][3]));
                        mx = fmaxf(mx, a);
                    }
                    mx = fmaxf(mx, __shfl_xor(mx, 16));
                    mx = fmaxf(mx, __shfl_xor(mx, 32));
                    vmax[qb] = mx;
                    need = need || (mx > m_run[qb] + 8.0f);
                }
                if (__any(need)) {
#pragma unroll
                    for (int qb = 0; qb < 2; qb++) {
                        float mn = fmaxf(m_run[qb], vmax[qb]);
                        float sf = __builtin_amdgcn_exp2f(m_run[qb] - mn);
                        m_run[qb] = mn;
                        l_run[qb] *= sf;
#pragma unroll
                        for (int r = 0; r < 4; r++) {
                            float sfr = __shfl(sf, l16 * 4 + r);
#pragma unroll
                            for (int nd = 0; nd < 4; nd++) oacc[qb][nd][r] *= sfr;
                        }
                    }
                }
                // ---- P = exp2(S - m), row-sum, packed swizzled LDS write
#pragma unroll
                for (int qb = 0; qb < 2; qb++) {
                    const int row = qb * 16 + l15;
                    const int rx = (row & 7) << 3;
                    float ps = 0.f;
#pragma unroll
                    for (int kb = 0; kb < 4; kb++) {
                        float p0 = __builtin_amdgcn_exp2f(sc[qb][kb][0] - m_run[qb]);
                        float p1 = __builtin_amdgcn_exp2f(sc[qb][kb][1] - m_run[qb]);
                        float p2 = __builtin_amdgcn_exp2f(sc[qb][kb][2] - m_run[qb]);
                        float p3 = __builtin_amdgcn_exp2f(sc[qb][kb][3] - m_run[qb]);
                        ps += (p0 + p1) + (p2 + p3);
                        unsigned int lo = (unsigned int)f2bf(p0) |
                                          ((unsigned int)f2bf(p1) << 16);
                        unsigned int hi = (unsigned int)f2bf(p2) |
                                          ((unsigned int)f2bf(p3) << 16);
                        int kel = (kb * 16 + l16 * 4) ^ rx;
                        *reinterpret_cast<unsigned int*>(&Ps[w][row * 64 + kel]) = lo;
                        *reinterpret_cast<unsigned int*>(&Ps[w][row * 64 + kel + 2]) = hi;
                    }
                    ps += __shfl_xor(ps, 16);
                    ps += __shfl_xor(ps, 32);
                    l_run[qb] += ps;
                }
                // ---- PV: oacc += P[32 x 64k] * V^T[64d x 64k]^T
#pragma unroll
                for (int kc = 0; kc < 2; kc++) {
                    short8 vb[4], pa[2];
#pragma unroll
                    for (int nd = 0; nd < 4; nd++) {
                        int row = nd * 16 + l15;
                        vb[nd] = *reinterpret_cast<const short8*>(
                            Vb + row * 64 + (((kc * 4 + l16) ^ (row & 7)) << 3));
                    }
#pragma unroll
                    for (int qb = 0; qb < 2; qb++) {
                        int row = qb * 16 + l15;
                        pa[qb] = *reinterpret_cast<const short8*>(
                            &Ps[w][row * 64 + (((kc * 4 + l16) ^ (row & 7)) << 3)]);
                    }
                    __builtin_amdgcn_s_setprio(1);
#pragma unroll
                    for (int qb = 0; qb < 2; qb++)
#pragma unroll
                        for (int nd = 0; nd < 4; nd++)
                            oacc[qb][nd] = __builtin_amdgcn_mfma_f32_16x16x32_bf16(
                                pa[qb], vb[nd], oacc[qb][nd], 0, 0, 0);
                    __builtin_amdgcn_s_setprio(0);
                }
            }
            __syncthreads();
        }

        // ---- finalize
        const int b_ = bh >> 4, h = bh & 15;
#pragma unroll
        for (int qb = 0; qb < 2; qb++) {
            float li = 1.0f / l_run[qb];
#pragma unroll
            for (int r = 0; r < 4; r++) {
                float lir = __shfl(li, l16 * 4 + r);
                int row = b_ * SEQ + q0 + w * 32 + qb * 16 + l16 * 4 + r;
#pragma unroll
                for (int nd = 0; nd < 4; nd++)
                    O[(size_t)row * EMBED + h * 64 + nd * 16 + l15] =
                        f2bf(oacc[qb][nd][r] * lir);
            }
        }
    }
}

extern "C" void kernel_launch(void* const* d_in, const int* in_sizes, int n_in,
                              void* d_out, int out_size, void* d_ws, size_t ws_size,
                              hipStream_t stream) {
    (void)in_sizes; (void)n_in; (void)out_size; (void)ws_size;
    const float* x  = (const float*)d_in[0];
    const float* Wq = (const float*)d_in[1];
    const float* bq = (const float*)d_in[2];
    const float* Wk = (const float*)d_in[3];
    const float* bk = (const float*)d_in[4];
    const float* Wv = (const float*)d_in[5];
    const float* bv = (const float*)d_in[6];
    const float* Wo = (const float*)d_in[7];
    const float* bo = (const float*)d_in[8];
    float* out = (float*)d_out;

    unsigned short* xb   = (unsigned short*)d_ws;
    unsigned short* Wqkv = xb + (size_t)NROWS * EMBED;          // [3][1024][1024]
    unsigned short* Wot  = Wqkv + (size_t)3 * EMBED * EMBED;
    unsigned short* Qb   = Wot + (size_t)EMBED * EMBED;         // [b,h,s,d]
    unsigned short* Kb   = Qb + (size_t)NROWS * EMBED;
    unsigned short* Vtb  = Kb + (size_t)NROWS * EMBED;          // [b,h,d,s]
    unsigned short* attn = Vtb + (size_t)NROWS * EMBED;         // [b*s][1024]
    int* unit_counter = (int*)(attn + (size_t)NROWS * EMBED);

    hipMemsetAsync(unit_counter, 0, sizeof(int), stream);

    cast_x_kernel<<<(NROWS * EMBED / 4 + 255) / 256, 256, 0, stream>>>(
        x, xb, NROWS * EMBED / 4);
    dim3 tgrid(32, 32), tblk(32, 8);
    transW_kernel<<<tgrid, tblk, 0, stream>>>(Wq, Wqkv);
    transW_kernel<<<tgrid, tblk, 0, stream>>>(Wk, Wqkv + (size_t)EMBED * EMBED);
    transW_kernel<<<tgrid, tblk, 0, stream>>>(Wv, Wqkv + (size_t)2 * EMBED * EMBED);
    transW_kernel<<<tgrid, tblk, 0, stream>>>(Wo, Wot);

    gemm_kernel<0><<<dim3(24, 32), 256, 0, stream>>>(
        xb, Wqkv, EMBED, Qb, Kb, Vtb, bq, bk, bv, nullptr, nullptr);

    attn_kernel<<<768, 256, 0, stream>>>(Qb, Kb, Vtb, attn, unit_counter);

    gemm_kernel<1><<<dim3(8, 32), 256, 0, stream>>>(
        attn, Wot, EMBED, nullptr, nullptr, nullptr, nullptr, nullptr, nullptr,
        out, bo);
}

// Round 4
// 119.741 us; speedup vs baseline: 1.1856x; 1.1856x over previous
//
#include <hip/hip_runtime.h>
#include <hip/hip_bf16.h>
#include <stdint.h>

#define EMBED 1024
#define HEADS 16
#define HDIM 64
#define BATCH 2
#define SEQ 2048
#define NROWS (BATCH*SEQ)

typedef __attribute__((ext_vector_type(8))) short short8;
typedef __attribute__((ext_vector_type(4))) float f32x4;

#define LOG2E 1.44269504088896f

__device__ __forceinline__ unsigned short f2bf(float f) {
    __hip_bfloat16 b = __float2bfloat16(f);
    return *reinterpret_cast<unsigned short*>(&b);
}

__device__ __forceinline__ void g2l16(const void* g, void* l) {
    __builtin_amdgcn_global_load_lds(
        (const __attribute__((address_space(1))) unsigned int*)g,
        (__attribute__((address_space(3))) unsigned int*)l, 16, 0, 0);
}

// ---------------- cast x (fp32 -> bf16), vectorized ----------------
__global__ void cast_x_kernel(const float* __restrict__ x,
                              unsigned short* __restrict__ xb, int n4) {
    int i = blockIdx.x * blockDim.x + threadIdx.x;
    if (i < n4) {
        float4 v = reinterpret_cast<const float4*>(x)[i];
        ushort4 o;
        o.x = f2bf(v.x); o.y = f2bf(v.y); o.z = f2bf(v.z); o.w = f2bf(v.w);
        reinterpret_cast<ushort4*>(xb)[i] = o;
    }
}

// ---------------- transpose + cast W [in][out] fp32 -> Wt [out][in] bf16 ----
__global__ void transW_kernel(const float* __restrict__ W,
                              unsigned short* __restrict__ Wt) {
    __shared__ float tile[32][33];
    int tx = threadIdx.x, ty = threadIdx.y;
#pragma unroll
    for (int r = 0; r < 4; r++) {
        int i = blockIdx.y * 32 + ty + r * 8;
        int o = blockIdx.x * 32 + tx;
        tile[ty + r * 8][tx] = W[(size_t)i * EMBED + o];
    }
    __syncthreads();
    int i2 = blockIdx.y * 32 + tx;
#pragma unroll
    for (int r = 0; r < 4; r++) {
        int o2 = blockIdx.x * 32 + ty + r * 8;
        Wt[(size_t)o2 * EMBED + i2] = f2bf(tile[tx][ty + r * 8]);
    }
}

// ---------------- GEMM: C[M][N] = A[M][K] * B[N][K]^T  (bf16 in, fp32 acc) --
template<int MODE>
__global__ __launch_bounds__(256)
void gemm_kernel(const unsigned short* __restrict__ A,
                 const unsigned short* __restrict__ B,
                 int K,
                 unsigned short* __restrict__ Qo,
                 unsigned short* __restrict__ Ko,
                 unsigned short* __restrict__ Vto,
                 const float* __restrict__ bq,
                 const float* __restrict__ bk,
                 const float* __restrict__ bvv,
                 float* __restrict__ Co,
                 const float* __restrict__ bo) {
    __shared__ __attribute__((aligned(16))) unsigned short As[128 * 64];
    __shared__ __attribute__((aligned(16))) unsigned short Bs[128 * 64];
    const int t = threadIdx.x;
    const int lane = t & 63;
    const int w = t >> 6;
    const int wr = w >> 1, wc = w & 1;
    const int l15 = lane & 15, l16 = lane >> 4;
    const int m0 = blockIdx.y * 128;
    const int n0 = blockIdx.x * 128;

    f32x4 acc[4][4];
#pragma unroll
    for (int i = 0; i < 4; i++)
#pragma unroll
        for (int j = 0; j < 4; j++) acc[i][j] = (f32x4){0.f, 0.f, 0.f, 0.f};

    for (int k0 = 0; k0 < K; k0 += 64) {
        __syncthreads();
#pragma unroll
        for (int i = 0; i < 4; i++) {
            int c = i * 256 + t;
            int row = c >> 3;
            int lc = (c & 7) ^ (row & 7);
            g2l16(A + (size_t)(m0 + row) * K + k0 + lc * 8,
                  As + (size_t)(i * 256 + (t & ~63)) * 8);
        }
#pragma unroll
        for (int i = 0; i < 4; i++) {
            int c = i * 256 + t;
            int row = c >> 3;
            int lc = (c & 7) ^ (row & 7);
            g2l16(B + (size_t)(n0 + row) * K + k0 + lc * 8,
                  Bs + (size_t)(i * 256 + (t & ~63)) * 8);
        }
        __syncthreads();
#pragma unroll
        for (int kk = 0; kk < 2; kk++) {
            short8 a[4], b[4];
#pragma unroll
            for (int ai = 0; ai < 4; ai++) {
                int row = wr * 64 + ai * 16 + l15;
                int ch = kk * 4 + l16;
                a[ai] = *reinterpret_cast<const short8*>(
                    As + row * 64 + ((ch ^ (row & 7)) << 3));
            }
#pragma unroll
            for (int bj = 0; bj < 4; bj++) {
                int row = wc * 64 + bj * 16 + l15;
                int ch = kk * 4 + l16;
                b[bj] = *reinterpret_cast<const short8*>(
                    Bs + row * 64 + ((ch ^ (row & 7)) << 3));
            }
            __builtin_amdgcn_s_setprio(1);
#pragma unroll
            for (int ai = 0; ai < 4; ai++)
#pragma unroll
                for (int bj = 0; bj < 4; bj++)
                    acc[ai][bj] = __builtin_amdgcn_mfma_f32_16x16x32_bf16(
                        a[ai], b[bj], acc[ai][bj], 0, 0, 0);
            __builtin_amdgcn_s_setprio(0);
        }
    }

    if (MODE == 0) {
        const int which = n0 >> 10;        // 0=Q 1=K 2=V
        const int coln = n0 & 1023;
        const float* bias = which == 0 ? bq : (which == 1 ? bk : bvv);
        // Q pre-scaled by softmax scale * LOG2E (softmax done in log2 domain)
        const float scale = which == 0 ? 0.125f * LOG2E : 1.0f;
#pragma unroll
        for (int ai = 0; ai < 4; ai++) {
            int rowb = m0 + wr * 64 + ai * 16 + l16 * 4;
            int b_ = rowb >> 11;
            int s = rowb & 2047;
#pragma unroll
            for (int bj = 0; bj < 4; bj++) {
                int col = coln + wc * 64 + bj * 16 + l15;
                float bsv = bias[col];
                int h = col >> 6, d = col & 63;
                if (which < 2) {
                    unsigned short* dst = (which == 0) ? Qo : Ko;
                    size_t base = ((size_t)(b_ * HEADS + h)) * SEQ * HDIM;
#pragma unroll
                    for (int r = 0; r < 4; r++) {
                        float v = (acc[ai][bj][r] + bsv) * scale;
                        dst[base + (size_t)(s + r) * HDIM + d] = f2bf(v);
                    }
                } else {
                    ushort4 pk;
                    pk.x = f2bf(acc[ai][bj][0] + bsv);
                    pk.y = f2bf(acc[ai][bj][1] + bsv);
                    pk.z = f2bf(acc[ai][bj][2] + bsv);
                    pk.w = f2bf(acc[ai][bj][3] + bsv);
                    size_t off = ((size_t)(b_ * HEADS + h) * HDIM + d) * SEQ + s;
                    *reinterpret_cast<ushort4*>(Vto + off) = pk;
                }
            }
        }
    } else {
#pragma unroll
        for (int ai = 0; ai < 4; ai++) {
            int rowb = m0 + wr * 64 + ai * 16 + l16 * 4;
#pragma unroll
            for (int bj = 0; bj < 4; bj++) {
                int col = n0 + wc * 64 + bj * 16 + l15;
                float bsv = bo[col];
#pragma unroll
                for (int r = 0; r < 4; r++)
                    Co[(size_t)(rowb + r) * EMBED + col] = acc[ai][bj][r] + bsv;
            }
        }
    }
}

// ---------------- causal flash attention ------------------------------------
// Q,K: [bh][s][64] bf16 (Q pre-scaled by 0.125*LOG2E); V: [bh][64][s] bf16.
// O: [b*s][1024] bf16. 4 waves x 32 q-rows = 128 q-rows/block; KV tile 64.
// Triple-buffered K/V staged via global_load_lds, counted s_waitcnt vmcnt(N)
// + raw s_barrier so prefetch (depth 2) stays in flight across barriers.
// Grid (16,32): qi = (y<16)? x : 15-x  -> blocks c and c+256 have
// complementary causal cost (34 tiles total), balancing every CU.
__device__ __forceinline__ void stage_kv(const unsigned short* __restrict__ Kg,
                                         const unsigned short* __restrict__ Vg,
                                         int kv0, unsigned short* Ksb,
                                         unsigned short* Vsb, int t) {
#pragma unroll
    for (int i = 0; i < 2; i++) {          // K tile [64 keys][64 d]
        int c = i * 256 + t;
        int row = c >> 3;
        int lc = (c & 7) ^ (row & 7);
        g2l16(Kg + (size_t)(kv0 + row) * HDIM + lc * 8,
              Ksb + (i * 256 + (t & ~63)) * 8);
    }
#pragma unroll
    for (int i = 0; i < 2; i++) {          // V^T tile [64 d][64 keys]
        int c = i * 256 + t;
        int d = c >> 3;
        int lc = (c & 7) ^ (d & 7);
        g2l16(Vg + (size_t)d * SEQ + kv0 + lc * 8,
              Vsb + (i * 256 + (t & ~63)) * 8);
    }
}

__global__ __launch_bounds__(256, 2)
void attn_kernel(const unsigned short* __restrict__ Q,
                 const unsigned short* __restrict__ Kk,
                 const unsigned short* __restrict__ Vt,
                 unsigned short* __restrict__ O) {
    __shared__ __attribute__((aligned(16))) unsigned short Ks[3][64 * 64];
    __shared__ __attribute__((aligned(16))) unsigned short Vs[3][64 * 64];
    __shared__ __attribute__((aligned(16))) unsigned short Ps[4][32 * 64];

    const int t = threadIdx.x;
    const int lane = t & 63;
    const int w = t >> 6;
    const int l15 = lane & 15, l16 = lane >> 4;
    const int bh = blockIdx.y;
    const int qi = (blockIdx.y < 16) ? blockIdx.x : 15 - blockIdx.x;
    const int q0 = qi * 128;
    const size_t base = (size_t)bh * SEQ * HDIM;
    const unsigned short* Kg = Kk + base;
    const unsigned short* Vg = Vt + base;
    const int qrow0 = q0 + w * 32;

    // Q fragments (B-operand) straight from global
    short8 qf[2][2];
    {
        const unsigned short* Qg = Q + base + (size_t)qrow0 * HDIM;
#pragma unroll
        for (int qb = 0; qb < 2; qb++)
#pragma unroll
            for (int kc = 0; kc < 2; kc++)
                qf[qb][kc] = *reinterpret_cast<const short8*>(
                    Qg + (qb * 16 + l15) * HDIM + (kc * 4 + l16) * 8);
    }

    f32x4 oacc[2][4];
#pragma unroll
    for (int qb = 0; qb < 2; qb++)
#pragma unroll
        for (int nd = 0; nd < 4; nd++) oacc[qb][nd] = (f32x4){0.f, 0.f, 0.f, 0.f};
    float m_run[2] = {-1e30f, -1e30f};
    float l_run[2] = {0.f, 0.f};

    const int ntiles = 2 * qi + 2;   // >= 2 always

    unsigned short *k0 = Ks[0], *k1 = Ks[1], *k2 = Ks[2];
    unsigned short *v0 = Vs[0], *v1 = Vs[1], *v2 = Vs[2];

    stage_kv(Kg, Vg, 0, k0, v0, t);
    stage_kv(Kg, Vg, 64, k1, v1, t);
    // require tile0 loads done; allow tile1's 4 loads in flight
    asm volatile("s_waitcnt vmcnt(4)" ::: "memory");
    __builtin_amdgcn_s_barrier();
    asm volatile("" ::: "memory");

    for (int tk = 0; tk < ntiles; tk++) {
        const int kv0 = tk * 64;
        const bool more2 = (tk + 2 < ntiles);
        if (more2) stage_kv(Kg, Vg, kv0 + 128, k2, v2, t);

        if (kv0 <= qrow0 + 31) {
            const unsigned short* Kb = k0;
            const unsigned short* Vb = v0;
            // ---- S^T = K * Q^T : rows = keys, cols = q
            f32x4 sc[2][4];
#pragma unroll
            for (int qb = 0; qb < 2; qb++)
#pragma unroll
                for (int kb = 0; kb < 4; kb++)
                    sc[qb][kb] = (f32x4){0.f, 0.f, 0.f, 0.f};
#pragma unroll
            for (int kc = 0; kc < 2; kc++) {
                short8 ka[4];
#pragma unroll
                for (int kb = 0; kb < 4; kb++) {
                    int row = kb * 16 + l15;
                    ka[kb] = *reinterpret_cast<const short8*>(
                        Kb + row * 64 + (((kc * 4 + l16) ^ (row & 7)) << 3));
                }
                __builtin_amdgcn_s_setprio(1);
#pragma unroll
                for (int qb = 0; qb < 2; qb++)
#pragma unroll
                    for (int kb = 0; kb < 4; kb++)
                        sc[qb][kb] = __builtin_amdgcn_mfma_f32_16x16x32_bf16(
                            ka[kb], qf[qb][kc], sc[qb][kb], 0, 0, 0);
                __builtin_amdgcn_s_setprio(0);
            }
            // ---- causal mask (diagonal tiles only)
            if (kv0 + 63 > qrow0) {
#pragma unroll
                for (int qb = 0; qb < 2; qb++) {
                    int q = qrow0 + qb * 16 + l15;
#pragma unroll
                    for (int kb = 0; kb < 4; kb++)
#pragma unroll
                        for (int r = 0; r < 4; r++) {
                            int k = kv0 + kb * 16 + l16 * 4 + r;
                            sc[qb][kb][r] = (k > q) ? -1e30f : sc[qb][kb][r];
                        }
                }
            }
            // ---- row max (in-register + 2 shuffles), defer-rescale vote
            float vmax[2];
            bool need = false;
#pragma unroll
            for (int qb = 0; qb < 2; qb++) {
                float mx = -1e30f;
#pragma unroll
                for (int kb = 0; kb < 4; kb++) {
                    float a = fmaxf(fmaxf(sc[qb][kb][0], sc[qb][kb][1]),
                                    fmaxf(sc[qb][kb][2], sc[qb][kb][3]));
                    mx = fmaxf(mx, a);
                }
                mx = fmaxf(mx, __shfl_xor(mx, 16));
                mx = fmaxf(mx, __shfl_xor(mx, 32));
                vmax[qb] = mx;
                need = need || (mx > m_run[qb] + 8.0f);
            }
            if (__any(need)) {
#pragma unroll
                for (int qb = 0; qb < 2; qb++) {
                    float mn = fmaxf(m_run[qb], vmax[qb]);
                    float sf = __builtin_amdgcn_exp2f(m_run[qb] - mn);
                    m_run[qb] = mn;
                    l_run[qb] *= sf;
#pragma unroll
                    for (int r = 0; r < 4; r++) {
                        float sfr = __shfl(sf, l16 * 4 + r);
#pragma unroll
                        for (int nd = 0; nd < 4; nd++) oacc[qb][nd][r] *= sfr;
                    }
                }
            }
            // ---- P = exp2(S - m), row-sum, packed swizzled LDS write
#pragma unroll
            for (int qb = 0; qb < 2; qb++) {
                const int row = qb * 16 + l15;
                const int rx = (row & 7) << 3;
                float ps = 0.f;
#pragma unroll
                for (int kb = 0; kb < 4; kb++) {
                    float p0 = __builtin_amdgcn_exp2f(sc[qb][kb][0] - m_run[qb]);
                    float p1 = __builtin_amdgcn_exp2f(sc[qb][kb][1] - m_run[qb]);
                    float p2 = __builtin_amdgcn_exp2f(sc[qb][kb][2] - m_run[qb]);
                    float p3 = __builtin_amdgcn_exp2f(sc[qb][kb][3] - m_run[qb]);
                    ps += (p0 + p1) + (p2 + p3);
                    unsigned int lo = (unsigned int)f2bf(p0) |
                                      ((unsigned int)f2bf(p1) << 16);
                    unsigned int hi = (unsigned int)f2bf(p2) |
                                      ((unsigned int)f2bf(p3) << 16);
                    int kel = (kb * 16 + l16 * 4) ^ rx;
                    *reinterpret_cast<unsigned int*>(&Ps[w][row * 64 + kel]) = lo;
                    *reinterpret_cast<unsigned int*>(&Ps[w][row * 64 + kel + 2]) = hi;
                }
                ps += __shfl_xor(ps, 16);
                ps += __shfl_xor(ps, 32);
                l_run[qb] += ps;
            }
            // ---- PV: oacc += P[32 x 64k] * V^T[64d x 64k]^T
#pragma unroll
            for (int kc = 0; kc < 2; kc++) {
                short8 vb[4], pa[2];
#pragma unroll
                for (int nd = 0; nd < 4; nd++) {
                    int row = nd * 16 + l15;
                    vb[nd] = *reinterpret_cast<const short8*>(
                        Vb + row * 64 + (((kc * 4 + l16) ^ (row & 7)) << 3));
                }
#pragma unroll
                for (int qb = 0; qb < 2; qb++) {
                    int row = qb * 16 + l15;
                    pa[qb] = *reinterpret_cast<const short8*>(
                        &Ps[w][row * 64 + (((kc * 4 + l16) ^ (row & 7)) << 3)]);
                }
                __builtin_amdgcn_s_setprio(1);
#pragma unroll
                for (int qb = 0; qb < 2; qb++)
#pragma unroll
                    for (int nd = 0; nd < 4; nd++)
                        oacc[qb][nd] = __builtin_amdgcn_mfma_f32_16x16x32_bf16(
                            pa[qb], vb[nd], oacc[qb][nd], 0, 0, 0);
                __builtin_amdgcn_s_setprio(0);
            }
        }

        if (tk + 1 < ntiles) {
            // require tile (tk+1) staged; allow tile (tk+2)'s 4 loads in flight
            if (more2) asm volatile("s_waitcnt vmcnt(4)" ::: "memory");
            else       asm volatile("s_waitcnt vmcnt(0)" ::: "memory");
            __builtin_amdgcn_s_barrier();
            asm volatile("" ::: "memory");
        }
        // rotate triple buffers
        unsigned short* kt = k0; k0 = k1; k1 = k2; k2 = kt;
        unsigned short* vt = v0; v0 = v1; v1 = v2; v2 = vt;
    }

    // ---- finalize
    const int b_ = bh >> 4, h = bh & 15;
#pragma unroll
    for (int qb = 0; qb < 2; qb++) {
        float li = 1.0f / l_run[qb];
#pragma unroll
        for (int r = 0; r < 4; r++) {
            float lir = __shfl(li, l16 * 4 + r);
            int row = b_ * SEQ + q0 + w * 32 + qb * 16 + l16 * 4 + r;
#pragma unroll
            for (int nd = 0; nd < 4; nd++)
                O[(size_t)row * EMBED + h * 64 + nd * 16 + l15] =
                    f2bf(oacc[qb][nd][r] * lir);
        }
    }
}

extern "C" void kernel_launch(void* const* d_in, const int* in_sizes, int n_in,
                              void* d_out, int out_size, void* d_ws, size_t ws_size,
                              hipStream_t stream) {
    (void)in_sizes; (void)n_in; (void)out_size; (void)ws_size;
    const float* x  = (const float*)d_in[0];
    const float* Wq = (const float*)d_in[1];
    const float* bq = (const float*)d_in[2];
    const float* Wk = (const float*)d_in[3];
    const float* bk = (const float*)d_in[4];
    const float* Wv = (const float*)d_in[5];
    const float* bv = (const float*)d_in[6];
    const float* Wo = (const float*)d_in[7];
    const float* bo = (const float*)d_in[8];
    float* out = (float*)d_out;

    unsigned short* xb   = (unsigned short*)d_ws;
    unsigned short* Wqkv = xb + (size_t)NROWS * EMBED;          // [3][1024][1024]
    unsigned short* Wot  = Wqkv + (size_t)3 * EMBED * EMBED;
    unsigned short* Qb   = Wot + (size_t)EMBED * EMBED;         // [b,h,s,d]
    unsigned short* Kb   = Qb + (size_t)NROWS * EMBED;
    unsigned short* Vtb  = Kb + (size_t)NROWS * EMBED;          // [b,h,d,s]
    unsigned short* attn = Vtb + (size_t)NROWS * EMBED;         // [b*s][1024]

    cast_x_kernel<<<(NROWS * EMBED / 4 + 255) / 256, 256, 0, stream>>>(
        x, xb, NROWS * EMBED / 4);
    dim3 tgrid(32, 32), tblk(32, 8);
    transW_kernel<<<tgrid, tblk, 0, stream>>>(Wq, Wqkv);
    transW_kernel<<<tgrid, tblk, 0, stream>>>(Wk, Wqkv + (size_t)EMBED * EMBED);
    transW_kernel<<<tgrid, tblk, 0, stream>>>(Wv, Wqkv + (size_t)2 * EMBED * EMBED);
    transW_kernel<<<tgrid, tblk, 0, stream>>>(Wo, Wot);

    gemm_kernel<0><<<dim3(24, 32), 256, 0, stream>>>(
        xb, Wqkv, EMBED, Qb, Kb, Vtb, bq, bk, bv, nullptr, nullptr);

    attn_kernel<<<dim3(16, 32), 256, 0, stream>>>(Qb, Kb, Vtb, attn);

    gemm_kernel<1><<<dim3(8, 32), 256, 0, stream>>>(
        attn, Wot, EMBED, nullptr, nullptr, nullptr, nullptr, nullptr, nullptr,
        out, bo);
}

// Round 6
// 119.476 us; speedup vs baseline: 1.1882x; 1.0022x over previous
//
#include <hip/hip_runtime.h>
#include <hip/hip_bf16.h>
#include <stdint.h>

#define EMBED 1024
#define HEADS 16
#define HDIM 64
#define BATCH 2
#define SEQ 2048
#define NROWS (BATCH*SEQ)

typedef __attribute__((ext_vector_type(8))) short short8;
typedef __attribute__((ext_vector_type(4))) float f32x4;
typedef __attribute__((ext_vector_type(2))) unsigned int uint2v;

#define LOG2E 1.44269504088896f

__device__ __forceinline__ unsigned short f2bf(float f) {
    __hip_bfloat16 b = __float2bfloat16(f);
    return *reinterpret_cast<unsigned short*>(&b);
}

__device__ __forceinline__ void g2l16(const void* g, void* l) {
    __builtin_amdgcn_global_load_lds(
        (const __attribute__((address_space(1))) unsigned int*)g,
        (__attribute__((address_space(3))) unsigned int*)l, 16, 0, 0);
}

// ---------------- cast x (fp32 -> bf16), vectorized ----------------
__global__ void cast_x_kernel(const float* __restrict__ x,
                              unsigned short* __restrict__ xb, int n4) {
    int i = blockIdx.x * blockDim.x + threadIdx.x;
    if (i < n4) {
        float4 v = reinterpret_cast<const float4*>(x)[i];
        ushort4 o;
        o.x = f2bf(v.x); o.y = f2bf(v.y); o.z = f2bf(v.z); o.w = f2bf(v.w);
        reinterpret_cast<ushort4*>(xb)[i] = o;
    }
}

// ---------------- transpose + cast W [in][out] fp32 -> Wt [out][in] bf16 ----
__global__ void transW_kernel(const float* __restrict__ W,
                              unsigned short* __restrict__ Wt) {
    __shared__ float tile[32][33];
    int tx = threadIdx.x, ty = threadIdx.y;
#pragma unroll
    for (int r = 0; r < 4; r++) {
        int i = blockIdx.y * 32 + ty + r * 8;
        int o = blockIdx.x * 32 + tx;
        tile[ty + r * 8][tx] = W[(size_t)i * EMBED + o];
    }
    __syncthreads();
    int i2 = blockIdx.y * 32 + tx;
#pragma unroll
    for (int r = 0; r < 4; r++) {
        int o2 = blockIdx.x * 32 + ty + r * 8;
        Wt[(size_t)o2 * EMBED + i2] = f2bf(tile[tx][ty + r * 8]);
    }
}

// ---------------- GEMM: C[M][N] = A[M][K] * B[N][K]^T  (bf16 in, fp32 acc) --
template<int MODE>
__global__ __launch_bounds__(256)
void gemm_kernel(const unsigned short* __restrict__ A,
                 const unsigned short* __restrict__ B,
                 int K,
                 unsigned short* __restrict__ Qo,
                 unsigned short* __restrict__ Ko,
                 unsigned short* __restrict__ Vto,
                 const float* __restrict__ bq,
                 const float* __restrict__ bk,
                 const float* __restrict__ bvv,
                 float* __restrict__ Co,
                 const float* __restrict__ bo) {
    __shared__ __attribute__((aligned(16))) unsigned short As[128 * 64];
    __shared__ __attribute__((aligned(16))) unsigned short Bs[128 * 64];
    const int t = threadIdx.x;
    const int lane = t & 63;
    const int w = t >> 6;
    const int wr = w >> 1, wc = w & 1;
    const int l15 = lane & 15, l16 = lane >> 4;
    const int m0 = blockIdx.y * 128;
    const int n0 = blockIdx.x * 128;

    f32x4 acc[4][4];
#pragma unroll
    for (int i = 0; i < 4; i++)
#pragma unroll
        for (int j = 0; j < 4; j++) acc[i][j] = (f32x4){0.f, 0.f, 0.f, 0.f};

    for (int k0 = 0; k0 < K; k0 += 64) {
        __syncthreads();
#pragma unroll
        for (int i = 0; i < 4; i++) {
            int c = i * 256 + t;
            int row = c >> 3;
            int lc = (c & 7) ^ (row & 7);
            g2l16(A + (size_t)(m0 + row) * K + k0 + lc * 8,
                  As + (size_t)(i * 256 + (t & ~63)) * 8);
        }
#pragma unroll
        for (int i = 0; i < 4; i++) {
            int c = i * 256 + t;
            int row = c >> 3;
            int lc = (c & 7) ^ (row & 7);
            g2l16(B + (size_t)(n0 + row) * K + k0 + lc * 8,
                  Bs + (size_t)(i * 256 + (t & ~63)) * 8);
        }
        __syncthreads();
#pragma unroll
        for (int kk = 0; kk < 2; kk++) {
            short8 a[4], b[4];
#pragma unroll
            for (int ai = 0; ai < 4; ai++) {
                int row = wr * 64 + ai * 16 + l15;
                int ch = kk * 4 + l16;
                a[ai] = *reinterpret_cast<const short8*>(
                    As + row * 64 + ((ch ^ (row & 7)) << 3));
            }
#pragma unroll
            for (int bj = 0; bj < 4; bj++) {
                int row = wc * 64 + bj * 16 + l15;
                int ch = kk * 4 + l16;
                b[bj] = *reinterpret_cast<const short8*>(
                    Bs + row * 64 + ((ch ^ (row & 7)) << 3));
            }
            __builtin_amdgcn_s_setprio(1);
#pragma unroll
            for (int ai = 0; ai < 4; ai++)
#pragma unroll
                for (int bj = 0; bj < 4; bj++)
                    acc[ai][bj] = __builtin_amdgcn_mfma_f32_16x16x32_bf16(
                        a[ai], b[bj], acc[ai][bj], 0, 0, 0);
            __builtin_amdgcn_s_setprio(0);
        }
    }

    if (MODE == 0) {
        const int which = n0 >> 10;        // 0=Q 1=K 2=V
        const int coln = n0 & 1023;
        const float* bias = which == 0 ? bq : (which == 1 ? bk : bvv);
        // Q pre-scaled by softmax scale * LOG2E (softmax done in log2 domain)
        const float scale = which == 0 ? 0.125f * LOG2E : 1.0f;
#pragma unroll
        for (int ai = 0; ai < 4; ai++) {
            int rowb = m0 + wr * 64 + ai * 16 + l16 * 4;
            int b_ = rowb >> 11;
            int s = rowb & 2047;
#pragma unroll
            for (int bj = 0; bj < 4; bj++) {
                int col = coln + wc * 64 + bj * 16 + l15;
                float bsv = bias[col];
                int h = col >> 6, d = col & 63;
                if (which < 2) {
                    unsigned short* dst = (which == 0) ? Qo : Ko;
                    size_t base = ((size_t)(b_ * HEADS + h)) * SEQ * HDIM;
#pragma unroll
                    for (int r = 0; r < 4; r++) {
                        float v = (acc[ai][bj][r] + bsv) * scale;
                        dst[base + (size_t)(s + r) * HDIM + d] = f2bf(v);
                    }
                } else {
                    ushort4 pk;
                    pk.x = f2bf(acc[ai][bj][0] + bsv);
                    pk.y = f2bf(acc[ai][bj][1] + bsv);
                    pk.z = f2bf(acc[ai][bj][2] + bsv);
                    pk.w = f2bf(acc[ai][bj][3] + bsv);
                    size_t off = ((size_t)(b_ * HEADS + h) * HDIM + d) * SEQ + s;
                    *reinterpret_cast<ushort4*>(Vto + off) = pk;
                }
            }
        }
    } else {
#pragma unroll
        for (int ai = 0; ai < 4; ai++) {
            int rowb = m0 + wr * 64 + ai * 16 + l16 * 4;
#pragma unroll
            for (int bj = 0; bj < 4; bj++) {
                int col = n0 + wc * 64 + bj * 16 + l15;
                float bsv = bo[col];
#pragma unroll
                for (int r = 0; r < 4; r++)
                    Co[(size_t)(rowb + r) * EMBED + col] = acc[ai][bj][r] + bsv;
            }
        }
    }
}

// ---------------- causal flash attention ------------------------------------
// Q,K: [bh][s][64] bf16 (Q pre-scaled by 0.125*LOG2E); V: [bh][64][s] bf16.
// O: [b*s][1024] bf16. 4 waves x 32 q-rows = 128 q-rows/block; KV tile 64.
// Triple-buffered K/V via global_load_lds + counted vmcnt(4) + raw s_barrier.
// Block mapping (512 linear blocks): id%8 = XCD (round-robin dispatch) ->
// bh group of 4 heads (2 MB K/V, fits 4 MB XCD L2); within XCD, CU c
// co-hosts s=c>>2 and s+8 -> qi = s / 15-s gives every CU exactly 34 tiles.
__device__ __forceinline__ void stage_kv(const unsigned short* __restrict__ Kg,
                                         const unsigned short* __restrict__ Vg,
                                         int kv0, unsigned short* Ksb,
                                         unsigned short* Vsb, int t) {
#pragma unroll
    for (int i = 0; i < 2; i++) {          // K tile [64 keys][64 d]
        int c = i * 256 + t;
        int row = c >> 3;
        int lc = (c & 7) ^ (row & 7);
        g2l16(Kg + (size_t)(kv0 + row) * HDIM + lc * 8,
              Ksb + (i * 256 + (t & ~63)) * 8);
    }
#pragma unroll
    for (int i = 0; i < 2; i++) {          // V^T tile [64 d][64 keys]
        int c = i * 256 + t;
        int d = c >> 3;
        int lc = (c & 7) ^ (d & 7);
        g2l16(Vg + (size_t)d * SEQ + kv0 + lc * 8,
              Vsb + (i * 256 + (t & ~63)) * 8);
    }
}

__global__ __launch_bounds__(256, 2)
void attn_kernel(const unsigned short* __restrict__ Q,
                 const unsigned short* __restrict__ Kk,
                 const unsigned short* __restrict__ Vt,
                 unsigned short* __restrict__ O) {
    __shared__ __attribute__((aligned(16))) unsigned short Ks[3][64 * 64];
    __shared__ __attribute__((aligned(16))) unsigned short Vs[3][64 * 64];
    __shared__ __attribute__((aligned(16))) unsigned short Ps[4][32 * 64];

    const int t = threadIdx.x;
    const int lane = t & 63;
    const int w = t >> 6;
    const int l15 = lane & 15, l16 = lane >> 4;

    // XCD-local head grouping + balanced qi pairing
    const int id = blockIdx.x;
    const int xcd = id & 7;
    const int u = id >> 3;            // 0..63 within XCD
    const int bh = xcd * 4 + (u & 3); // 4 heads per XCD -> 2 MB K/V in L2
    const int s_ = u >> 2;            // 0..15
    const int qi = (s_ < 8) ? s_ : 23 - s_;  // CU pairs (s,s+8): qi s & 15-s
    const int q0 = qi * 128;
    const size_t base = (size_t)bh * SEQ * HDIM;
    const unsigned short* Kg = Kk + base;
    const unsigned short* Vg = Vt + base;
    const int qrow0 = q0 + w * 32;

    // Q fragments (B-operand) straight from global
    short8 qf[2][2];
    {
        const unsigned short* Qg = Q + base + (size_t)qrow0 * HDIM;
#pragma unroll
        for (int qb = 0; qb < 2; qb++)
#pragma unroll
            for (int kc = 0; kc < 2; kc++)
                qf[qb][kc] = *reinterpret_cast<const short8*>(
                    Qg + (qb * 16 + l15) * HDIM + (kc * 4 + l16) * 8);
    }

    f32x4 oacc[2][4];
#pragma unroll
    for (int qb = 0; qb < 2; qb++)
#pragma unroll
        for (int nd = 0; nd < 4; nd++) oacc[qb][nd] = (f32x4){0.f, 0.f, 0.f, 0.f};
    float m_run[2] = {-1e30f, -1e30f};
    float l_run[2] = {0.f, 0.f};

    const int ntiles = 2 * qi + 2;   // >= 2 always

    unsigned short *k0 = Ks[0], *k1 = Ks[1], *k2 = Ks[2];
    unsigned short *v0 = Vs[0], *v1 = Vs[1], *v2 = Vs[2];

    stage_kv(Kg, Vg, 0, k0, v0, t);
    stage_kv(Kg, Vg, 64, k1, v1, t);
    // require tile0 loads done; allow tile1's 4 loads in flight
    asm volatile("s_waitcnt vmcnt(4)" ::: "memory");
    __builtin_amdgcn_s_barrier();
    asm volatile("" ::: "memory");

    for (int tk = 0; tk < ntiles; tk++) {
        const int kv0 = tk * 64;
        const bool more2 = (tk + 2 < ntiles);
        if (more2) stage_kv(Kg, Vg, kv0 + 128, k2, v2, t);

        if (kv0 <= qrow0 + 31) {
            const unsigned short* Kb = k0;
            const unsigned short* Vb = v0;
            // ---- S^T = K * Q^T : rows = keys, cols = q
            f32x4 sc[2][4];
#pragma unroll
            for (int qb = 0; qb < 2; qb++)
#pragma unroll
                for (int kb = 0; kb < 4; kb++)
                    sc[qb][kb] = (f32x4){0.f, 0.f, 0.f, 0.f};
#pragma unroll
            for (int kc = 0; kc < 2; kc++) {
                short8 ka[4];
#pragma unroll
                for (int kb = 0; kb < 4; kb++) {
                    int row = kb * 16 + l15;
                    ka[kb] = *reinterpret_cast<const short8*>(
                        Kb + row * 64 + (((kc * 4 + l16) ^ (row & 7)) << 3));
                }
                __builtin_amdgcn_s_setprio(1);
#pragma unroll
                for (int qb = 0; qb < 2; qb++)
#pragma unroll
                    for (int kb = 0; kb < 4; kb++)
                        sc[qb][kb] = __builtin_amdgcn_mfma_f32_16x16x32_bf16(
                            ka[kb], qf[qb][kc], sc[qb][kb], 0, 0, 0);
                __builtin_amdgcn_s_setprio(0);
            }
            // ---- causal mask (diagonal tiles only)
            if (kv0 + 63 > qrow0) {
#pragma unroll
                for (int qb = 0; qb < 2; qb++) {
                    int q = qrow0 + qb * 16 + l15;
#pragma unroll
                    for (int kb = 0; kb < 4; kb++)
#pragma unroll
                        for (int r = 0; r < 4; r++) {
                            int k = kv0 + kb * 16 + l16 * 4 + r;
                            sc[qb][kb][r] = (k > q) ? -1e30f : sc[qb][kb][r];
                        }
                }
            }
            // ---- row max (in-register + 2 shuffles), defer-rescale vote
            float vmax[2];
            bool need = false;
#pragma unroll
            for (int qb = 0; qb < 2; qb++) {
                float mx = -1e30f;
#pragma unroll
                for (int kb = 0; kb < 4; kb++) {
                    float a = fmaxf(fmaxf(sc[qb][kb][0], sc[qb][kb][1]),
                                    fmaxf(sc[qb][kb][2], sc[qb][kb][3]));
                    mx = fmaxf(mx, a);
                }
                mx = fmaxf(mx, __shfl_xor(mx, 16));
                mx = fmaxf(mx, __shfl_xor(mx, 32));
                vmax[qb] = mx;
                need = need || (mx > m_run[qb] + 8.0f);
            }
            if (__any(need)) {
#pragma unroll
                for (int qb = 0; qb < 2; qb++) {
                    float mn = fmaxf(m_run[qb], vmax[qb]);
                    float sf = __builtin_amdgcn_exp2f(m_run[qb] - mn);
                    m_run[qb] = mn;
                    l_run[qb] *= sf;
#pragma unroll
                    for (int r = 0; r < 4; r++) {
                        float sfr = __shfl(sf, l16 * 4 + r);
#pragma unroll
                        for (int nd = 0; nd < 4; nd++) oacc[qb][nd][r] *= sfr;
                    }
                }
            }
            // ---- P = exp2(S - m), row-sum, packed swizzled LDS write (b64)
#pragma unroll
            for (int qb = 0; qb < 2; qb++) {
                const int row = qb * 16 + l15;
                const int rx = (row & 7) << 3;
                float ps = 0.f;
#pragma unroll
                for (int kb = 0; kb < 4; kb++) {
                    float p0 = __builtin_amdgcn_exp2f(sc[qb][kb][0] - m_run[qb]);
                    float p1 = __builtin_amdgcn_exp2f(sc[qb][kb][1] - m_run[qb]);
                    float p2 = __builtin_amdgcn_exp2f(sc[qb][kb][2] - m_run[qb]);
                    float p3 = __builtin_amdgcn_exp2f(sc[qb][kb][3] - m_run[qb]);
                    ps += (p0 + p1) + (p2 + p3);
                    uint2v pk;
                    pk.x = (unsigned int)f2bf(p0) | ((unsigned int)f2bf(p1) << 16);
                    pk.y = (unsigned int)f2bf(p2) | ((unsigned int)f2bf(p3) << 16);
                    int kel = (kb * 16 + l16 * 4) ^ rx;
                    *reinterpret_cast<uint2v*>(&Ps[w][row * 64 + kel]) = pk;
                }
                ps += __shfl_xor(ps, 16);
                ps += __shfl_xor(ps, 32);
                l_run[qb] += ps;
            }
            // ---- PV: oacc += P[32 x 64k] * V^T[64d x 64k]^T
#pragma unroll
            for (int kc = 0; kc < 2; kc++) {
                short8 vb[4], pa[2];
#pragma unroll
                for (int nd = 0; nd < 4; nd++) {
                    int row = nd * 16 + l15;
                    vb[nd] = *reinterpret_cast<const short8*>(
                        Vb + row * 64 + (((kc * 4 + l16) ^ (row & 7)) << 3));
                }
#pragma unroll
                for (int qb = 0; qb < 2; qb++) {
                    int row = qb * 16 + l15;
                    pa[qb] = *reinterpret_cast<const short8*>(
                        &Ps[w][row * 64 + (((kc * 4 + l16) ^ (row & 7)) << 3)]);
                }
                __builtin_amdgcn_s_setprio(1);
#pragma unroll
                for (int qb = 0; qb < 2; qb++)
#pragma unroll
                    for (int nd = 0; nd < 4; nd++)
                        oacc[qb][nd] = __builtin_amdgcn_mfma_f32_16x16x32_bf16(
                            pa[qb], vb[nd], oacc[qb][nd], 0, 0, 0);
                __builtin_amdgcn_s_setprio(0);
            }
        }

        if (tk + 1 < ntiles) {
            // require tile (tk+1) staged; allow tile (tk+2)'s 4 loads in flight
            if (more2) asm volatile("s_waitcnt vmcnt(4)" ::: "memory");
            else       asm volatile("s_waitcnt vmcnt(0)" ::: "memory");
            __builtin_amdgcn_s_barrier();
            asm volatile("" ::: "memory");
        }
        // rotate triple buffers
        unsigned short* kt = k0; k0 = k1; k1 = k2; k2 = kt;
        unsigned short* vt = v0; v0 = v1; v1 = v2; v2 = vt;
    }

    // ---- finalize
    const int b_ = bh >> 4, h = bh & 15;
#pragma unroll
    for (int qb = 0; qb < 2; qb++) {
        float li = 1.0f / l_run[qb];
#pragma unroll
        for (int r = 0; r < 4; r++) {
            float lir = __shfl(li, l16 * 4 + r);
            int row = b_ * SEQ + q0 + w * 32 + qb * 16 + l16 * 4 + r;
#pragma unroll
            for (int nd = 0; nd < 4; nd++)
                O[(size_t)row * EMBED + h * 64 + nd * 16 + l15] =
                    f2bf(oacc[qb][nd][r] * lir);
        }
    }
}

extern "C" void kernel_launch(void* const* d_in, const int* in_sizes, int n_in,
                              void* d_out, int out_size, void* d_ws, size_t ws_size,
                              hipStream_t stream) {
    (void)in_sizes; (void)n_in; (void)out_size; (void)ws_size;
    const float* x  = (const float*)d_in[0];
    const float* Wq = (const float*)d_in[1];
    const float* bq = (const float*)d_in[2];
    const float* Wk = (const float*)d_in[3];
    const float* bk = (const float*)d_in[4];
    const float* Wv = (const float*)d_in[5];
    const float* bv = (const float*)d_in[6];
    const float* Wo = (const float*)d_in[7];
    const float* bo = (const float*)d_in[8];
    float* out = (float*)d_out;

    unsigned short* xb   = (unsigned short*)d_ws;
    unsigned short* Wqkv = xb + (size_t)NROWS * EMBED;          // [3][1024][1024]
    unsigned short* Wot  = Wqkv + (size_t)3 * EMBED * EMBED;
    unsigned short* Qb   = Wot + (size_t)EMBED * EMBED;         // [b,h,s,d]
    unsigned short* Kb   = Qb + (size_t)NROWS * EMBED;
    unsigned short* Vtb  = Kb + (size_t)NROWS * EMBED;          // [b,h,d,s]
    unsigned short* attn = Vtb + (size_t)NROWS * EMBED;         // [b*s][1024]

    cast_x_kernel<<<(NROWS * EMBED / 4 + 255) / 256, 256, 0, stream>>>(
        x, xb, NROWS * EMBED / 4);
    dim3 tgrid(32, 32), tblk(32, 8);
    transW_kernel<<<tgrid, tblk, 0, stream>>>(Wq, Wqkv);
    transW_kernel<<<tgrid, tblk, 0, stream>>>(Wk, Wqkv + (size_t)EMBED * EMBED);
    transW_kernel<<<tgrid, tblk, 0, stream>>>(Wv, Wqkv + (size_t)2 * EMBED * EMBED);
    transW_kernel<<<tgrid, tblk, 0, stream>>>(Wo, Wot);

    gemm_kernel<0><<<dim3(24, 32), 256, 0, stream>>>(
        xb, Wqkv, EMBED, Qb, Kb, Vtb, bq, bk, bv, nullptr, nullptr);

    attn_kernel<<<512, 256, 0, stream>>>(Qb, Kb, Vtb, attn);

    gemm_kernel<1><<<dim3(8, 32), 256, 0, stream>>>(
        attn, Wot, EMBED, nullptr, nullptr, nullptr, nullptr, nullptr, nullptr,
        out, bo);
}

// Round 7
// 113.080 us; speedup vs baseline: 1.2554x; 1.0566x over previous
//
#include <hip/hip_runtime.h>
#include <hip/hip_bf16.h>
#include <stdint.h>

#define EMBED 1024
#define HEADS 16
#define HDIM 64
#define BATCH 2
#define SEQ 2048
#define NROWS (BATCH*SEQ)

typedef __attribute__((ext_vector_type(8))) short short8;
typedef __attribute__((ext_vector_type(4))) float f32x4;
typedef __attribute__((ext_vector_type(2))) unsigned int uint2v;

#define LOG2E 1.44269504088896f

__device__ __forceinline__ unsigned short f2bf(float f) {
    __hip_bfloat16 b = __float2bfloat16(f);
    return *reinterpret_cast<unsigned short*>(&b);
}

__device__ __forceinline__ void g2l16(const void* g, void* l) {
    __builtin_amdgcn_global_load_lds(
        (const __attribute__((address_space(1))) unsigned int*)g,
        (__attribute__((address_space(3))) unsigned int*)l, 16, 0, 0);
}

// ---------------- cast x (fp32 -> bf16), vectorized ----------------
__global__ void cast_x_kernel(const float* __restrict__ x,
                              unsigned short* __restrict__ xb, int n4) {
    int i = blockIdx.x * blockDim.x + threadIdx.x;
    if (i < n4) {
        float4 v = reinterpret_cast<const float4*>(x)[i];
        ushort4 o;
        o.x = f2bf(v.x); o.y = f2bf(v.y); o.z = f2bf(v.z); o.w = f2bf(v.w);
        reinterpret_cast<ushort4*>(xb)[i] = o;
    }
}

// ---------------- transpose + cast W [in][out] fp32 -> Wt [out][in] bf16 ----
__global__ void transW_kernel(const float* __restrict__ W,
                              unsigned short* __restrict__ Wt) {
    __shared__ float tile[32][33];
    int tx = threadIdx.x, ty = threadIdx.y;
#pragma unroll
    for (int r = 0; r < 4; r++) {
        int i = blockIdx.y * 32 + ty + r * 8;
        int o = blockIdx.x * 32 + tx;
        tile[ty + r * 8][tx] = W[(size_t)i * EMBED + o];
    }
    __syncthreads();
    int i2 = blockIdx.y * 32 + tx;
#pragma unroll
    for (int r = 0; r < 4; r++) {
        int o2 = blockIdx.x * 32 + ty + r * 8;
        Wt[(size_t)o2 * EMBED + i2] = f2bf(tile[tx][ty + r * 8]);
    }
}

// ---------------- GEMM: C[M][N] = A[M][K] * B[N][K]^T  (bf16 in, fp32 acc) --
template<int MODE>
__global__ __launch_bounds__(256)
void gemm_kernel(const unsigned short* __restrict__ A,
                 const unsigned short* __restrict__ B,
                 int K,
                 unsigned short* __restrict__ Qo,
                 unsigned short* __restrict__ Ko,
                 unsigned short* __restrict__ Vto,
                 const float* __restrict__ bq,
                 const float* __restrict__ bk,
                 const float* __restrict__ bvv,
                 float* __restrict__ Co,
                 const float* __restrict__ bo) {
    __shared__ __attribute__((aligned(16))) unsigned short As[128 * 64];
    __shared__ __attribute__((aligned(16))) unsigned short Bs[128 * 64];
    const int t = threadIdx.x;
    const int lane = t & 63;
    const int w = t >> 6;
    const int wr = w >> 1, wc = w & 1;
    const int l15 = lane & 15, l16 = lane >> 4;
    const int m0 = blockIdx.y * 128;
    const int n0 = blockIdx.x * 128;

    f32x4 acc[4][4];
#pragma unroll
    for (int i = 0; i < 4; i++)
#pragma unroll
        for (int j = 0; j < 4; j++) acc[i][j] = (f32x4){0.f, 0.f, 0.f, 0.f};

    for (int k0 = 0; k0 < K; k0 += 64) {
        __syncthreads();
#pragma unroll
        for (int i = 0; i < 4; i++) {
            int c = i * 256 + t;
            int row = c >> 3;
            int lc = (c & 7) ^ (row & 7);
            g2l16(A + (size_t)(m0 + row) * K + k0 + lc * 8,
                  As + (size_t)(i * 256 + (t & ~63)) * 8);
        }
#pragma unroll
        for (int i = 0; i < 4; i++) {
            int c = i * 256 + t;
            int row = c >> 3;
            int lc = (c & 7) ^ (row & 7);
            g2l16(B + (size_t)(n0 + row) * K + k0 + lc * 8,
                  Bs + (size_t)(i * 256 + (t & ~63)) * 8);
        }
        __syncthreads();
#pragma unroll
        for (int kk = 0; kk < 2; kk++) {
            short8 a[4], b[4];
#pragma unroll
            for (int ai = 0; ai < 4; ai++) {
                int row = wr * 64 + ai * 16 + l15;
                int ch = kk * 4 + l16;
                a[ai] = *reinterpret_cast<const short8*>(
                    As + row * 64 + ((ch ^ (row & 7)) << 3));
            }
#pragma unroll
            for (int bj = 0; bj < 4; bj++) {
                int row = wc * 64 + bj * 16 + l15;
                int ch = kk * 4 + l16;
                b[bj] = *reinterpret_cast<const short8*>(
                    Bs + row * 64 + ((ch ^ (row & 7)) << 3));
            }
            __builtin_amdgcn_s_setprio(1);
#pragma unroll
            for (int ai = 0; ai < 4; ai++)
#pragma unroll
                for (int bj = 0; bj < 4; bj++)
                    acc[ai][bj] = __builtin_amdgcn_mfma_f32_16x16x32_bf16(
                        a[ai], b[bj], acc[ai][bj], 0, 0, 0);
            __builtin_amdgcn_s_setprio(0);
        }
    }

    if (MODE == 0) {
        const int which = n0 >> 10;        // 0=Q 1=K 2=V
        const int coln = n0 & 1023;
        const float* bias = which == 0 ? bq : (which == 1 ? bk : bvv);
        // Q pre-scaled by softmax scale * LOG2E (softmax done in log2 domain)
        const float scale = which == 0 ? 0.125f * LOG2E : 1.0f;
#pragma unroll
        for (int ai = 0; ai < 4; ai++) {
            int rowb = m0 + wr * 64 + ai * 16 + l16 * 4;
            int b_ = rowb >> 11;
            int s = rowb & 2047;
#pragma unroll
            for (int bj = 0; bj < 4; bj++) {
                int col = coln + wc * 64 + bj * 16 + l15;
                float bsv = bias[col];
                int h = col >> 6, d = col & 63;
                if (which < 2) {
                    unsigned short* dst = (which == 0) ? Qo : Ko;
                    size_t base = ((size_t)(b_ * HEADS + h)) * SEQ * HDIM;
#pragma unroll
                    for (int r = 0; r < 4; r++) {
                        float v = (acc[ai][bj][r] + bsv) * scale;
                        dst[base + (size_t)(s + r) * HDIM + d] = f2bf(v);
                    }
                } else {
                    ushort4 pk;
                    pk.x = f2bf(acc[ai][bj][0] + bsv);
                    pk.y = f2bf(acc[ai][bj][1] + bsv);
                    pk.z = f2bf(acc[ai][bj][2] + bsv);
                    pk.w = f2bf(acc[ai][bj][3] + bsv);
                    size_t off = ((size_t)(b_ * HEADS + h) * HDIM + d) * SEQ + s;
                    *reinterpret_cast<ushort4*>(Vto + off) = pk;
                }
            }
        }
    } else {
#pragma unroll
        for (int ai = 0; ai < 4; ai++) {
            int rowb = m0 + wr * 64 + ai * 16 + l16 * 4;
#pragma unroll
            for (int bj = 0; bj < 4; bj++) {
                int col = n0 + wc * 64 + bj * 16 + l15;
                float bsv = bo[col];
#pragma unroll
                for (int r = 0; r < 4; r++)
                    Co[(size_t)(rowb + r) * EMBED + col] = acc[ai][bj][r] + bsv;
            }
        }
    }
}

// ---------------- causal flash attention ------------------------------------
// Q,K: [bh][s][64] bf16 (Q pre-scaled by 0.125*LOG2E); V: [bh][64][s] bf16.
// O: [b*s][1024] bf16. QBLK=64 (4 waves x 16 q-rows); KV tile 64; K/V
// double-buffered (issue-early/wait-late: vmcnt(0)+barrier at loop top,
// stage tk+1 right after, compute fills the latency). LDS 40 KB -> 4
// blocks/CU (16 waves). Grid 1024: id%8 = XCD -> 4-head group (2 MB K/V
// fits 4 MB XCD L2); co-resident qi sets {s,s+8,31-s,23-s} = 62 tiles/CU.
__device__ __forceinline__ void stage_kv(const unsigned short* __restrict__ Kg,
                                         const unsigned short* __restrict__ Vg,
                                         int kv0, unsigned short* Ksb,
                                         unsigned short* Vsb, int t) {
#pragma unroll
    for (int i = 0; i < 2; i++) {          // K tile [64 keys][64 d]
        int c = i * 256 + t;
        int row = c >> 3;
        int lc = (c & 7) ^ (row & 7);
        g2l16(Kg + (size_t)(kv0 + row) * HDIM + lc * 8,
              Ksb + (i * 256 + (t & ~63)) * 8);
    }
#pragma unroll
    for (int i = 0; i < 2; i++) {          // V^T tile [64 d][64 keys]
        int c = i * 256 + t;
        int d = c >> 3;
        int lc = (c & 7) ^ (d & 7);
        g2l16(Vg + (size_t)d * SEQ + kv0 + lc * 8,
              Vsb + (i * 256 + (t & ~63)) * 8);
    }
}

__global__ __launch_bounds__(256, 4)
void attn_kernel(const unsigned short* __restrict__ Q,
                 const unsigned short* __restrict__ Kk,
                 const unsigned short* __restrict__ Vt,
                 unsigned short* __restrict__ O) {
    __shared__ __attribute__((aligned(16))) unsigned short Ks[2][64 * 64];
    __shared__ __attribute__((aligned(16))) unsigned short Vs[2][64 * 64];
    __shared__ __attribute__((aligned(16))) unsigned short Ps[4][16 * 64];

    const int t = threadIdx.x;
    const int lane = t & 63;
    const int w = t >> 6;
    const int l15 = lane & 15, l16 = lane >> 4;

    // XCD-local head grouping + 4-way balanced qi sets
    const int id = blockIdx.x;
    const int xcd = id & 7;
    const int u = id >> 3;             // 0..127 within XCD
    const int bh = xcd * 4 + (u & 3);  // 4 heads per XCD -> 2 MB K/V in L2
    const int su = u >> 2;             // 0..31
    const int qi = (su < 16) ? su : 47 - su;   // co-resident: s,s+8,31-s,23-s
    const int q0 = qi * 64;
    const size_t base = (size_t)bh * SEQ * HDIM;
    const unsigned short* Kg = Kk + base;
    const unsigned short* Vg = Vt + base;
    const int qrow0 = q0 + w * 16;

    // Q fragments (B-operand) straight from global: lane = q-col l15
    short8 qf[2];
    {
        const unsigned short* Qg = Q + base + (size_t)qrow0 * HDIM;
#pragma unroll
        for (int kc = 0; kc < 2; kc++)
            qf[kc] = *reinterpret_cast<const short8*>(
                Qg + l15 * HDIM + (kc * 4 + l16) * 8);
    }

    f32x4 oacc[4];
#pragma unroll
    for (int nd = 0; nd < 4; nd++) oacc[nd] = (f32x4){0.f, 0.f, 0.f, 0.f};
    float m_run = -1e30f, l_run = 0.f;

    const int ntiles = qi + 1;

    stage_kv(Kg, Vg, 0, Ks[0], Vs[0], t);

    for (int tk = 0; tk < ntiles; tk++) {
        const int cur = tk & 1;
        // wait own stage of tile tk; barrier => everyone's stage landed AND
        // everyone is done reading buf[cur^1] (read during iter tk-1)
        asm volatile("s_waitcnt vmcnt(0)" ::: "memory");
        __builtin_amdgcn_s_barrier();
        asm volatile("" ::: "memory");
        if (tk + 1 < ntiles)
            stage_kv(Kg, Vg, (tk + 1) * 64, Ks[cur ^ 1], Vs[cur ^ 1], t);

        const unsigned short* Kb = Ks[cur];
        const unsigned short* Vb = Vs[cur];

        // ---- S^T = K * Q^T : C rows = keys (l16*4+r per kb), cols = q (l15)
        f32x4 sc[4];
#pragma unroll
        for (int kb = 0; kb < 4; kb++) sc[kb] = (f32x4){0.f, 0.f, 0.f, 0.f};
#pragma unroll
        for (int kc = 0; kc < 2; kc++) {
            short8 ka[4];
#pragma unroll
            for (int kb = 0; kb < 4; kb++) {
                int row = kb * 16 + l15;
                ka[kb] = *reinterpret_cast<const short8*>(
                    Kb + row * 64 + (((kc * 4 + l16) ^ (row & 7)) << 3));
            }
            __builtin_amdgcn_s_setprio(1);
#pragma unroll
            for (int kb = 0; kb < 4; kb++)
                sc[kb] = __builtin_amdgcn_mfma_f32_16x16x32_bf16(
                    ka[kb], qf[kc], sc[kb], 0, 0, 0);
            __builtin_amdgcn_s_setprio(0);
        }
        // ---- causal mask (diagonal tile only): key kb*16+l16*4+r vs q w*16+l15
        if (tk == ntiles - 1) {
            const int qloc = w * 16 + l15;
#pragma unroll
            for (int kb = 0; kb < 4; kb++)
#pragma unroll
                for (int r = 0; r < 4; r++) {
                    int kloc = kb * 16 + l16 * 4 + r;
                    sc[kb][r] = (kloc > qloc) ? -1e30f : sc[kb][r];
                }
        }
        // ---- row max over 16 lane-local keys + 2 shuffles; defer-rescale
        float mx = -1e30f;
#pragma unroll
        for (int kb = 0; kb < 4; kb++)
            mx = fmaxf(mx, fmaxf(fmaxf(sc[kb][0], sc[kb][1]),
                                 fmaxf(sc[kb][2], sc[kb][3])));
        mx = fmaxf(mx, __shfl_xor(mx, 16));
        mx = fmaxf(mx, __shfl_xor(mx, 32));
        if (__any(mx > m_run + 8.0f)) {
            float mn = fmaxf(m_run, mx);
            float sf = __builtin_amdgcn_exp2f(m_run - mn);
            m_run = mn;
            l_run *= sf;
#pragma unroll
            for (int r = 0; r < 4; r++) {
                float sfr = __shfl(sf, l16 * 4 + r);
#pragma unroll
                for (int nd = 0; nd < 4; nd++) oacc[nd][r] *= sfr;
            }
        }
        // ---- P = exp2(S - m), row-sum, packed swizzled LDS write (b64)
        {
            const int rx = (l15 & 7) << 3;
            float ps = 0.f;
#pragma unroll
            for (int kb = 0; kb < 4; kb++) {
                float p0 = __builtin_amdgcn_exp2f(sc[kb][0] - m_run);
                float p1 = __builtin_amdgcn_exp2f(sc[kb][1] - m_run);
                float p2 = __builtin_amdgcn_exp2f(sc[kb][2] - m_run);
                float p3 = __builtin_amdgcn_exp2f(sc[kb][3] - m_run);
                ps += (p0 + p1) + (p2 + p3);
                uint2v pk;
                pk.x = (unsigned int)f2bf(p0) | ((unsigned int)f2bf(p1) << 16);
                pk.y = (unsigned int)f2bf(p2) | ((unsigned int)f2bf(p3) << 16);
                int kel = (kb * 16 + l16 * 4) ^ rx;
                *reinterpret_cast<uint2v*>(&Ps[w][l15 * 64 + kel]) = pk;
            }
            ps += __shfl_xor(ps, 16);
            ps += __shfl_xor(ps, 32);
            l_run += ps;
        }
        // ---- PV: oacc += P[16q x 64k] * V^T[64d x 64k]^T
#pragma unroll
        for (int kc = 0; kc < 2; kc++) {
            short8 vb[4], pa;
#pragma unroll
            for (int nd = 0; nd < 4; nd++) {
                int row = nd * 16 + l15;
                vb[nd] = *reinterpret_cast<const short8*>(
                    Vb + row * 64 + (((kc * 4 + l16) ^ (row & 7)) << 3));
            }
            pa = *reinterpret_cast<const short8*>(
                &Ps[w][l15 * 64 + (((kc * 4 + l16) ^ (l15 & 7)) << 3)]);
            __builtin_amdgcn_s_setprio(1);
#pragma unroll
            for (int nd = 0; nd < 4; nd++)
                oacc[nd] = __builtin_amdgcn_mfma_f32_16x16x32_bf16(
                    pa, vb[nd], oacc[nd], 0, 0, 0);
            __builtin_amdgcn_s_setprio(0);
        }
    }

    // ---- finalize
    const int b_ = bh >> 4, h = bh & 15;
    float li = 1.0f / l_run;
#pragma unroll
    for (int r = 0; r < 4; r++) {
        float lir = __shfl(li, l16 * 4 + r);
        int row = b_ * SEQ + qrow0 + l16 * 4 + r;
#pragma unroll
        for (int nd = 0; nd < 4; nd++)
            O[(size_t)row * EMBED + h * 64 + nd * 16 + l15] =
                f2bf(oacc[nd][r] * lir);
    }
}

extern "C" void kernel_launch(void* const* d_in, const int* in_sizes, int n_in,
                              void* d_out, int out_size, void* d_ws, size_t ws_size,
                              hipStream_t stream) {
    (void)in_sizes; (void)n_in; (void)out_size; (void)ws_size;
    const float* x  = (const float*)d_in[0];
    const float* Wq = (const float*)d_in[1];
    const float* bq = (const float*)d_in[2];
    const float* Wk = (const float*)d_in[3];
    const float* bk = (const float*)d_in[4];
    const float* Wv = (const float*)d_in[5];
    const float* bv = (const float*)d_in[6];
    const float* Wo = (const float*)d_in[7];
    const float* bo = (const float*)d_in[8];
    float* out = (float*)d_out;

    unsigned short* xb   = (unsigned short*)d_ws;
    unsigned short* Wqkv = xb + (size_t)NROWS * EMBED;          // [3][1024][1024]
    unsigned short* Wot  = Wqkv + (size_t)3 * EMBED * EMBED;
    unsigned short* Qb   = Wot + (size_t)EMBED * EMBED;         // [b,h,s,d]
    unsigned short* Kb   = Qb + (size_t)NROWS * EMBED;
    unsigned short* Vtb  = Kb + (size_t)NROWS * EMBED;          // [b,h,d,s]
    unsigned short* attn = Vtb + (size_t)NROWS * EMBED;         // [b*s][1024]

    cast_x_kernel<<<(NROWS * EMBED / 4 + 255) / 256, 256, 0, stream>>>(
        x, xb, NROWS * EMBED / 4);
    dim3 tgrid(32, 32), tblk(32, 8);
    transW_kernel<<<tgrid, tblk, 0, stream>>>(Wq, Wqkv);
    transW_kernel<<<tgrid, tblk, 0, stream>>>(Wk, Wqkv + (size_t)EMBED * EMBED);
    transW_kernel<<<tgrid, tblk, 0, stream>>>(Wv, Wqkv + (size_t)2 * EMBED * EMBED);
    transW_kernel<<<tgrid, tblk, 0, stream>>>(Wo, Wot);

    gemm_kernel<0><<<dim3(24, 32), 256, 0, stream>>>(
        xb, Wqkv, EMBED, Qb, Kb, Vtb, bq, bk, bv, nullptr, nullptr);

    attn_kernel<<<1024, 256, 0, stream>>>(Qb, Kb, Vtb, attn);

    gemm_kernel<1><<<dim3(8, 32), 256, 0, stream>>>(
        attn, Wot, EMBED, nullptr, nullptr, nullptr, nullptr, nullptr, nullptr,
        out, bo);
}

// Round 8
// 111.297 us; speedup vs baseline: 1.2755x; 1.0160x over previous
//
#include <hip/hip_runtime.h>
#include <hip/hip_bf16.h>
#include <stdint.h>

#define EMBED 1024
#define HEADS 16
#define HDIM 64
#define BATCH 2
#define SEQ 2048
#define NROWS (BATCH*SEQ)

typedef __attribute__((ext_vector_type(8))) short short8;
typedef __attribute__((ext_vector_type(4))) float f32x4;
typedef __attribute__((ext_vector_type(2))) unsigned int uint2v;

#define LOG2E 1.44269504088896f

__device__ __forceinline__ unsigned short f2bf(float f) {
    __hip_bfloat16 b = __float2bfloat16(f);
    return *reinterpret_cast<unsigned short*>(&b);
}

__device__ __forceinline__ void g2l16(const void* g, void* l) {
    __builtin_amdgcn_global_load_lds(
        (const __attribute__((address_space(1))) unsigned int*)g,
        (__attribute__((address_space(3))) unsigned int*)l, 16, 0, 0);
}

// ---------------- cast x (fp32 -> bf16), vectorized ----------------
__global__ void cast_x_kernel(const float* __restrict__ x,
                              unsigned short* __restrict__ xb, int n4) {
    int i = blockIdx.x * blockDim.x + threadIdx.x;
    if (i < n4) {
        float4 v = reinterpret_cast<const float4*>(x)[i];
        ushort4 o;
        o.x = f2bf(v.x); o.y = f2bf(v.y); o.z = f2bf(v.z); o.w = f2bf(v.w);
        reinterpret_cast<ushort4*>(xb)[i] = o;
    }
}

// ---------------- transpose + cast W [in][out] fp32 -> Wt [out][in] bf16 ----
__global__ void transW_kernel(const float* __restrict__ W,
                              unsigned short* __restrict__ Wt) {
    __shared__ float tile[32][33];
    int tx = threadIdx.x, ty = threadIdx.y;
#pragma unroll
    for (int r = 0; r < 4; r++) {
        int i = blockIdx.y * 32 + ty + r * 8;
        int o = blockIdx.x * 32 + tx;
        tile[ty + r * 8][tx] = W[(size_t)i * EMBED + o];
    }
    __syncthreads();
    int i2 = blockIdx.y * 32 + tx;
#pragma unroll
    for (int r = 0; r < 4; r++) {
        int o2 = blockIdx.x * 32 + ty + r * 8;
        Wt[(size_t)o2 * EMBED + i2] = f2bf(tile[tx][ty + r * 8]);
    }
}

// ---------------- GEMM: C[M][N] = A[M][K] * B[N][K]^T  (bf16 in, fp32 acc) --
template<int MODE>
__global__ __launch_bounds__(256)
void gemm_kernel(const unsigned short* __restrict__ A,
                 const unsigned short* __restrict__ B,
                 int K,
                 unsigned short* __restrict__ Qo,
                 unsigned short* __restrict__ Ko,
                 unsigned short* __restrict__ Vto,
                 const float* __restrict__ bq,
                 const float* __restrict__ bk,
                 const float* __restrict__ bvv,
                 float* __restrict__ Co,
                 const float* __restrict__ bo) {
    __shared__ __attribute__((aligned(16))) unsigned short As[128 * 64];
    __shared__ __attribute__((aligned(16))) unsigned short Bs[128 * 64];
    const int t = threadIdx.x;
    const int lane = t & 63;
    const int w = t >> 6;
    const int wr = w >> 1, wc = w & 1;
    const int l15 = lane & 15, l16 = lane >> 4;
    const int m0 = blockIdx.y * 128;
    const int n0 = blockIdx.x * 128;

    f32x4 acc[4][4];
#pragma unroll
    for (int i = 0; i < 4; i++)
#pragma unroll
        for (int j = 0; j < 4; j++) acc[i][j] = (f32x4){0.f, 0.f, 0.f, 0.f};

    for (int k0 = 0; k0 < K; k0 += 64) {
        __syncthreads();
#pragma unroll
        for (int i = 0; i < 4; i++) {
            int c = i * 256 + t;
            int row = c >> 3;
            int lc = (c & 7) ^ (row & 7);
            g2l16(A + (size_t)(m0 + row) * K + k0 + lc * 8,
                  As + (size_t)(i * 256 + (t & ~63)) * 8);
        }
#pragma unroll
        for (int i = 0; i < 4; i++) {
            int c = i * 256 + t;
            int row = c >> 3;
            int lc = (c & 7) ^ (row & 7);
            g2l16(B + (size_t)(n0 + row) * K + k0 + lc * 8,
                  Bs + (size_t)(i * 256 + (t & ~63)) * 8);
        }
        __syncthreads();
#pragma unroll
        for (int kk = 0; kk < 2; kk++) {
            short8 a[4], b[4];
#pragma unroll
            for (int ai = 0; ai < 4; ai++) {
                int row = wr * 64 + ai * 16 + l15;
                int ch = kk * 4 + l16;
                a[ai] = *reinterpret_cast<const short8*>(
                    As + row * 64 + ((ch ^ (row & 7)) << 3));
            }
#pragma unroll
            for (int bj = 0; bj < 4; bj++) {
                int row = wc * 64 + bj * 16 + l15;
                int ch = kk * 4 + l16;
                b[bj] = *reinterpret_cast<const short8*>(
                    Bs + row * 64 + ((ch ^ (row & 7)) << 3));
            }
            __builtin_amdgcn_s_setprio(1);
#pragma unroll
            for (int ai = 0; ai < 4; ai++)
#pragma unroll
                for (int bj = 0; bj < 4; bj++)
                    acc[ai][bj] = __builtin_amdgcn_mfma_f32_16x16x32_bf16(
                        a[ai], b[bj], acc[ai][bj], 0, 0, 0);
            __builtin_amdgcn_s_setprio(0);
        }
    }

    if (MODE == 0) {
        const int which = n0 >> 10;        // 0=Q 1=K 2=V
        const int coln = n0 & 1023;
        const float* bias = which == 0 ? bq : (which == 1 ? bk : bvv);
        // Q pre-scaled by softmax scale * LOG2E (softmax done in log2 domain)
        const float scale = which == 0 ? 0.125f * LOG2E : 1.0f;
#pragma unroll
        for (int ai = 0; ai < 4; ai++) {
            int rowb = m0 + wr * 64 + ai * 16 + l16 * 4;
            int b_ = rowb >> 11;
            int s = rowb & 2047;
#pragma unroll
            for (int bj = 0; bj < 4; bj++) {
                int col = coln + wc * 64 + bj * 16 + l15;
                float bsv = bias[col];
                int h = col >> 6, d = col & 63;
                if (which < 2) {
                    unsigned short* dst = (which == 0) ? Qo : Ko;
                    size_t base = ((size_t)(b_ * HEADS + h)) * SEQ * HDIM;
#pragma unroll
                    for (int r = 0; r < 4; r++) {
                        float v = (acc[ai][bj][r] + bsv) * scale;
                        dst[base + (size_t)(s + r) * HDIM + d] = f2bf(v);
                    }
                } else {
                    ushort4 pk;
                    pk.x = f2bf(acc[ai][bj][0] + bsv);
                    pk.y = f2bf(acc[ai][bj][1] + bsv);
                    pk.z = f2bf(acc[ai][bj][2] + bsv);
                    pk.w = f2bf(acc[ai][bj][3] + bsv);
                    size_t off = ((size_t)(b_ * HEADS + h) * HDIM + d) * SEQ + s;
                    *reinterpret_cast<ushort4*>(Vto + off) = pk;
                }
            }
        }
    } else {
#pragma unroll
        for (int ai = 0; ai < 4; ai++) {
            int rowb = m0 + wr * 64 + ai * 16 + l16 * 4;
#pragma unroll
            for (int bj = 0; bj < 4; bj++) {
                int col = n0 + wc * 64 + bj * 16 + l15;
                float bsv = bo[col];
#pragma unroll
                for (int r = 0; r < 4; r++)
                    Co[(size_t)(rowb + r) * EMBED + col] = acc[ai][bj][r] + bsv;
            }
        }
    }
}

// ---------------- causal flash attention (software-pipelined) ---------------
// Q,K: [bh][s][64] bf16 (Q pre-scaled by 0.125*LOG2E); V: [bh][64][s] bf16.
// O: [b*s][1024] bf16. QBLK=64 (4 waves x 16 q-rows); KV tile 64; double-buf.
// Pipeline: iter t does {softmax+PV of tile t-1 (pre-barrier, old bufs)} then
// {vmcnt(0); barrier; stage(t+1); QK^T(t) -> other sc set}. QK^T/PV MFMA
// results are consumed one iteration later -> latency hidden; per-iter
// critical path ~= softmax VALU chain only. Mask applied only in epilogue
// (only the last tile is diagonal). sc double-buffered via static scA/scB.
__device__ __forceinline__ void stage_kv(const unsigned short* __restrict__ Kg,
                                         const unsigned short* __restrict__ Vg,
                                         int kv0, unsigned short* Ksb,
                                         unsigned short* Vsb, int t) {
#pragma unroll
    for (int i = 0; i < 2; i++) {          // K tile [64 keys][64 d]
        int c = i * 256 + t;
        int row = c >> 3;
        int lc = (c & 7) ^ (row & 7);
        g2l16(Kg + (size_t)(kv0 + row) * HDIM + lc * 8,
              Ksb + (i * 256 + (t & ~63)) * 8);
    }
#pragma unroll
    for (int i = 0; i < 2; i++) {          // V^T tile [64 d][64 keys]
        int c = i * 256 + t;
        int d = c >> 3;
        int lc = (c & 7) ^ (d & 7);
        g2l16(Vg + (size_t)d * SEQ + kv0 + lc * 8,
              Vsb + (i * 256 + (t & ~63)) * 8);
    }
}

__global__ __launch_bounds__(256, 4)
void attn_kernel(const unsigned short* __restrict__ Q,
                 const unsigned short* __restrict__ Kk,
                 const unsigned short* __restrict__ Vt,
                 unsigned short* __restrict__ O) {
    __shared__ __attribute__((aligned(16))) unsigned short Ks[2][64 * 64];
    __shared__ __attribute__((aligned(16))) unsigned short Vs[2][64 * 64];
    __shared__ __attribute__((aligned(16))) unsigned short Ps[4][16 * 64];

    const int t = threadIdx.x;
    const int lane = t & 63;
    const int w = t >> 6;
    const int l15 = lane & 15, l16 = lane >> 4;

    // XCD-local head grouping + 4-way balanced qi sets
    const int id = blockIdx.x;
    const int xcd = id & 7;
    const int u = id >> 3;             // 0..127 within XCD
    const int bh = xcd * 4 + (u & 3);  // 4 heads per XCD -> 2 MB K/V in L2
    const int su = u >> 2;             // 0..31
    const int qi = (su < 16) ? su : 47 - su;   // co-resident: s,s+8,31-s,23-s
    const int q0 = qi * 64;
    const size_t base = (size_t)bh * SEQ * HDIM;
    const unsigned short* Kg = Kk + base;
    const unsigned short* Vg = Vt + base;
    const int qrow0 = q0 + w * 16;

    // Q fragments (B-operand) straight from global: lane = q-col l15
    short8 qf[2];
    {
        const unsigned short* Qg = Q + base + (size_t)qrow0 * HDIM;
#pragma unroll
        for (int kc = 0; kc < 2; kc++)
            qf[kc] = *reinterpret_cast<const short8*>(
                Qg + l15 * HDIM + (kc * 4 + l16) * 8);
    }

    f32x4 oacc[4];
#pragma unroll
    for (int nd = 0; nd < 4; nd++) oacc[nd] = (f32x4){0.f, 0.f, 0.f, 0.f};
    float m_run = -1e30f, l_run = 0.f;

    const int nt = qi + 1;

    // ---- QK^T of tile tt from staged K buffer -> sc (results used next iter)
    auto qkt = [&](f32x4 (&sc)[4], const unsigned short* Kb) {
#pragma unroll
        for (int kb = 0; kb < 4; kb++) sc[kb] = (f32x4){0.f, 0.f, 0.f, 0.f};
#pragma unroll
        for (int kc = 0; kc < 2; kc++) {
            short8 ka[4];
#pragma unroll
            for (int kb = 0; kb < 4; kb++) {
                int row = kb * 16 + l15;
                ka[kb] = *reinterpret_cast<const short8*>(
                    Kb + row * 64 + (((kc * 4 + l16) ^ (row & 7)) << 3));
            }
            __builtin_amdgcn_s_setprio(1);
#pragma unroll
            for (int kb = 0; kb < 4; kb++)
                sc[kb] = __builtin_amdgcn_mfma_f32_16x16x32_bf16(
                    ka[kb], qf[kc], sc[kb], 0, 0, 0);
            __builtin_amdgcn_s_setprio(0);
        }
    };

    // ---- softmax + PV for the tile whose scores are in sc (V in Vb)
    auto softmax_pv = [&](f32x4 (&sc)[4], const unsigned short* Vb, bool diag) {
        if (diag) {
            const int qloc = w * 16 + l15;
#pragma unroll
            for (int kb = 0; kb < 4; kb++)
#pragma unroll
                for (int r = 0; r < 4; r++) {
                    int kloc = kb * 16 + l16 * 4 + r;
                    sc[kb][r] = (kloc > qloc) ? -1e30f : sc[kb][r];
                }
        }
        float mx = -1e30f;
#pragma unroll
        for (int kb = 0; kb < 4; kb++)
            mx = fmaxf(mx, fmaxf(fmaxf(sc[kb][0], sc[kb][1]),
                                 fmaxf(sc[kb][2], sc[kb][3])));
        mx = fmaxf(mx, __shfl_xor(mx, 16));
        mx = fmaxf(mx, __shfl_xor(mx, 32));
        if (__any(mx > m_run + 8.0f)) {
            float mn = fmaxf(m_run, mx);
            float sf = __builtin_amdgcn_exp2f(m_run - mn);
            m_run = mn;
            l_run *= sf;
#pragma unroll
            for (int r = 0; r < 4; r++) {
                float sfr = __shfl(sf, l16 * 4 + r);
#pragma unroll
                for (int nd = 0; nd < 4; nd++) oacc[nd][r] *= sfr;
            }
        }
        {
            const int rx = (l15 & 7) << 3;
            float ps = 0.f;
#pragma unroll
            for (int kb = 0; kb < 4; kb++) {
                float p0 = __builtin_amdgcn_exp2f(sc[kb][0] - m_run);
                float p1 = __builtin_amdgcn_exp2f(sc[kb][1] - m_run);
                float p2 = __builtin_amdgcn_exp2f(sc[kb][2] - m_run);
                float p3 = __builtin_amdgcn_exp2f(sc[kb][3] - m_run);
                ps += (p0 + p1) + (p2 + p3);
                uint2v pk;
                pk.x = (unsigned int)f2bf(p0) | ((unsigned int)f2bf(p1) << 16);
                pk.y = (unsigned int)f2bf(p2) | ((unsigned int)f2bf(p3) << 16);
                int kel = (kb * 16 + l16 * 4) ^ rx;
                *reinterpret_cast<uint2v*>(&Ps[w][l15 * 64 + kel]) = pk;
            }
            ps += __shfl_xor(ps, 16);
            ps += __shfl_xor(ps, 32);
            l_run += ps;
        }
#pragma unroll
        for (int kc = 0; kc < 2; kc++) {
            short8 vb[4], pa;
#pragma unroll
            for (int nd = 0; nd < 4; nd++) {
                int row = nd * 16 + l15;
                vb[nd] = *reinterpret_cast<const short8*>(
                    Vb + row * 64 + (((kc * 4 + l16) ^ (row & 7)) << 3));
            }
            pa = *reinterpret_cast<const short8*>(
                &Ps[w][l15 * 64 + (((kc * 4 + l16) ^ (l15 & 7)) << 3)]);
            __builtin_amdgcn_s_setprio(1);
#pragma unroll
            for (int nd = 0; nd < 4; nd++)
                oacc[nd] = __builtin_amdgcn_mfma_f32_16x16x32_bf16(
                    pa, vb[nd], oacc[nd], 0, 0, 0);
            __builtin_amdgcn_s_setprio(0);
        }
    };

    // ---- pipelined step: softmax+PV(tt-1) pre-barrier; QK^T(tt) post-barrier
    auto step = [&](f32x4 (&cur)[4], f32x4 (&nxt)[4], int tt) {
        softmax_pv(cur, Vs[(tt - 1) & 1], false);
        asm volatile("s_waitcnt vmcnt(0)" ::: "memory");
        __builtin_amdgcn_s_barrier();
        asm volatile("" ::: "memory");
        if (tt + 1 < nt)
            stage_kv(Kg, Vg, (tt + 1) * 64, Ks[(tt + 1) & 1], Vs[(tt + 1) & 1], t);
        qkt(nxt, Ks[tt & 1]);
    };

    f32x4 scA[4], scB[4];

    // prologue: stage tile 0, wait, stage tile 1 (in flight), QK^T(0)
    stage_kv(Kg, Vg, 0, Ks[0], Vs[0], t);
    asm volatile("s_waitcnt vmcnt(0)" ::: "memory");
    __builtin_amdgcn_s_barrier();
    asm volatile("" ::: "memory");
    if (nt > 1) stage_kv(Kg, Vg, 64, Ks[1], Vs[1], t);
    qkt(scA, Ks[0]);

    int tt = 1;
    for (; tt + 1 < nt; tt += 2) {
        step(scA, scB, tt);
        step(scB, scA, tt + 1);
    }
    if (tt < nt) {
        step(scA, scB, tt);
#pragma unroll
        for (int kb = 0; kb < 4; kb++) scA[kb] = scB[kb];
    }
    // epilogue: last (diagonal) tile
    softmax_pv(scA, Vs[(nt - 1) & 1], true);

    // ---- finalize
    const int b_ = bh >> 4, h = bh & 15;
    float li = 1.0f / l_run;
#pragma unroll
    for (int r = 0; r < 4; r++) {
        float lir = __shfl(li, l16 * 4 + r);
        int row = b_ * SEQ + qrow0 + l16 * 4 + r;
#pragma unroll
        for (int nd = 0; nd < 4; nd++)
            O[(size_t)row * EMBED + h * 64 + nd * 16 + l15] =
                f2bf(oacc[nd][r] * lir);
    }
}

extern "C" void kernel_launch(void* const* d_in, const int* in_sizes, int n_in,
                              void* d_out, int out_size, void* d_ws, size_t ws_size,
                              hipStream_t stream) {
    (void)in_sizes; (void)n_in; (void)out_size; (void)ws_size;
    const float* x  = (const float*)d_in[0];
    const float* Wq = (const float*)d_in[1];
    const float* bq = (const float*)d_in[2];
    const float* Wk = (const float*)d_in[3];
    const float* bk = (const float*)d_in[4];
    const float* Wv = (const float*)d_in[5];
    const float* bv = (const float*)d_in[6];
    const float* Wo = (const float*)d_in[7];
    const float* bo = (const float*)d_in[8];
    float* out = (float*)d_out;

    unsigned short* xb   = (unsigned short*)d_ws;
    unsigned short* Wqkv = xb + (size_t)NROWS * EMBED;          // [3][1024][1024]
    unsigned short* Wot  = Wqkv + (size_t)3 * EMBED * EMBED;
    unsigned short* Qb   = Wot + (size_t)EMBED * EMBED;         // [b,h,s,d]
    unsigned short* Kb   = Qb + (size_t)NROWS * EMBED;
    unsigned short* Vtb  = Kb + (size_t)NROWS * EMBED;          // [b,h,d,s]
    unsigned short* attn = Vtb + (size_t)NROWS * EMBED;         // [b*s][1024]

    cast_x_kernel<<<(NROWS * EMBED / 4 + 255) / 256, 256, 0, stream>>>(
        x, xb, NROWS * EMBED / 4);
    dim3 tgrid(32, 32), tblk(32, 8);
    transW_kernel<<<tgrid, tblk, 0, stream>>>(Wq, Wqkv);
    transW_kernel<<<tgrid, tblk, 0, stream>>>(Wk, Wqkv + (size_t)EMBED * EMBED);
    transW_kernel<<<tgrid, tblk, 0, stream>>>(Wv, Wqkv + (size_t)2 * EMBED * EMBED);
    transW_kernel<<<tgrid, tblk, 0, stream>>>(Wo, Wot);

    gemm_kernel<0><<<dim3(24, 32), 256, 0, stream>>>(
        xb, Wqkv, EMBED, Qb, Kb, Vtb, bq, bk, bv, nullptr, nullptr);

    attn_kernel<<<1024, 256, 0, stream>>>(Qb, Kb, Vtb, attn);

    gemm_kernel<1><<<dim3(8, 32), 256, 0, stream>>>(
        attn, Wot, EMBED, nullptr, nullptr, nullptr, nullptr, nullptr, nullptr,
        out, bo);
}